// Round 14
// baseline (1206.568 us; speedup 1.0000x reference)
//
#include <hip/hip_runtime.h>
#include <stdint.h>

// ---------------------------------------------------------------------------
// PaLM forward (DEPTH=4, DIM=1024, HEADS=16 MQA, DIM_HEAD=64, SEQ=2048,
// VOCAB=32000).  bf16 MFMA GEMMs (fp32 accum), fp32 residual stream,
// split-bf16 (hi+lo) QK^T.  wi AND logits on the 256x256 8-phase schedule
// (counted vmcnt + st_16x32 swizzle + setprio); wi epilogue fused (q/k
// hi-lo split, v->vT scatter, ff*swish(gate)->aof via interleaved wiT).
// wo: 2-phase split-K=2 partials merged in fused residual+rmsnorm.
// Flash: wave-pair KV-split (round-11 measured-best).
// ---------------------------------------------------------------------------

typedef __attribute__((ext_vector_type(8))) __bf16 bf16x8;
typedef __attribute__((ext_vector_type(4))) __bf16 bf16x4;
typedef __attribute__((ext_vector_type(8))) short s16x8;
typedef __attribute__((ext_vector_type(4))) float f32x4;

#define SEQ   2048
#define DIM   1024
#define NHEAD 16
#define DHEAD 64
#define FUSEN 9344   // 1024 q + 64 k + 64 v + 4096 ff + 4096 gate
#define WIN   9472   // FUSEN padded to x256 for the 256^2 wi GEMM
#define QKW   1088   // q+k columns -> hi/lo bf16 pair (precise attention)
#define FFIN  4096
#define VOCAB 32000
#define AFW   5120   // merged activation width: ao(1024) | ffact(4096)
#define LOG2E 1.44269504f

__device__ __forceinline__ f32x4 mfma16(bf16x8 a, bf16x8 b, f32x4 c) {
  return __builtin_amdgcn_mfma_f32_16x16x32_bf16(
      __builtin_bit_cast(s16x8, a), __builtin_bit_cast(s16x8, b), c, 0, 0, 0);
}

__device__ __forceinline__ void load_lds16(const __bf16* g, __bf16* l) {
  __builtin_amdgcn_global_load_lds(
      (const __attribute__((address_space(1))) uint32_t*)g,
      (__attribute__((address_space(3))) uint32_t*)l, 16, 0, 0);
}

// ---------------- elementwise / prep kernels -------------------------------

__global__ void cast_k(const float* __restrict__ in, __bf16* __restrict__ out, int n8) {
  int i = blockIdx.x * 256 + threadIdx.x;
  if (i >= n8) return;
  const float4* p = (const float4*)in + (size_t)i * 2;
  float4 a = p[0], b = p[1];
  bf16x8 o;
  o[0] = (__bf16)a.x; o[1] = (__bf16)a.y; o[2] = (__bf16)a.z; o[3] = (__bf16)a.w;
  o[4] = (__bf16)b.x; o[5] = (__bf16)b.y; o[6] = (__bf16)b.z; o[7] = (__bf16)b.w;
  *(bf16x8*)(out + (size_t)i * 8) = o;
}

// ff/gate interleave permutation for wiT rows (dst row for source col c):
// q/k/v (c<1152) unchanged; ff i -> 1152+32*(i/16)+(i%16); gate i -> +16.
__device__ __forceinline__ int permcol(int c) {
  if (c < 1152) return c;
  if (c < 5248) { int i = c - 1152; return 1152 + ((i >> 4) << 5) + (i & 15); }
  int i = c - 5248; return 1152 + ((i >> 4) << 5) + 16 + (i & 15);
}

// batched: wi [L][DIM][FUSEN] fp32 -> wiT4 [L][perm(FUSEN) of WIN][DIM] bf16.
__global__ __launch_bounds__(256) void transpose_wi_k(
    const float* __restrict__ in, __bf16* __restrict__ out) {
  __shared__ float tile[64][65];
  int l = blockIdx.z;
  int tx = threadIdx.x & 63, ty = threadIdx.x >> 6;   // 64 x 4
  int c0 = blockIdx.x * 64, r0 = blockIdx.y * 64;
  const float* inl = in + (size_t)l * DIM * FUSEN;
  __bf16* outl = out + (size_t)l * WIN * DIM;
  for (int i = ty; i < 64; i += 4)
    tile[i][tx] = inl[(size_t)(r0 + i) * FUSEN + c0 + tx];
  __syncthreads();
  for (int i = ty; i < 64; i += 4)
    outl[(size_t)permcol(c0 + i) * DIM + r0 + tx] = (__bf16)tile[tx][i];
}

// batched generic: in [L][R][C] fp32 -> out [L][C][ldo] bf16 at col offset co.
__global__ __launch_bounds__(256) void transpose_b_k(
    const float* __restrict__ in, __bf16* __restrict__ out,
    int R, int C, int ldo, int co, size_t outLstride) {
  __shared__ float tile[64][65];
  int l = blockIdx.z;
  int tx = threadIdx.x & 63, ty = threadIdx.x >> 6;
  int c0 = blockIdx.x * 64, r0 = blockIdx.y * 64;
  const float* inl = in + (size_t)l * R * C;
  __bf16* outl = out + (size_t)l * outLstride;
  for (int i = ty; i < 64; i += 4)
    tile[i][tx] = inl[(size_t)(r0 + i) * C + c0 + tx];
  __syncthreads();
  for (int i = ty; i < 64; i += 4)
    outl[(size_t)(c0 + i) * ldo + co + r0 + tx] = (__bf16)tile[tx][i];
}

// fused (gather|residual) + rmsnorm.
// MODE 0: v = emb[tokens[n]]; write xn = v.
// MODE 1: v = x + p0 + p1 (p = [2][SEQ][DIM]); write xn = v.
// MODE 2: v = x + p0 + p1; no xn write (final norm).
template <int MODE>
__global__ __launch_bounds__(256) void rmsnorm_fuse_k(
    const float* __restrict__ x, const float* __restrict__ p,
    const int* __restrict__ tokens, const float* __restrict__ emb,
    const float* __restrict__ gamma, float* __restrict__ xn,
    __bf16* __restrict__ h) {
  int n = blockIdx.x;
  float4 v;
  if (MODE == 0) {
    int tok = tokens[n];
    v = ((const float4*)(emb + (size_t)tok * DIM))[threadIdx.x];
    ((float4*)(xn + (size_t)n * DIM))[threadIdx.x] = v;
  } else {
    v = ((const float4*)(x + (size_t)n * DIM))[threadIdx.x];
    float4 a = ((const float4*)(p + (size_t)n * DIM))[threadIdx.x];
    float4 b = ((const float4*)(p + (size_t)(SEQ + n) * DIM))[threadIdx.x];
    v.x += a.x + b.x; v.y += a.y + b.y; v.z += a.z + b.z; v.w += a.w + b.w;
    if (MODE == 1)
      ((float4*)(xn + (size_t)n * DIM))[threadIdx.x] = v;
  }
  float ssq = v.x * v.x + v.y * v.y + v.z * v.z + v.w * v.w;
  for (int m = 32; m >= 1; m >>= 1) ssq += __shfl_xor(ssq, m, 64);
  __shared__ float red[4];
  if ((threadIdx.x & 63) == 0) red[threadIdx.x >> 6] = ssq;
  __syncthreads();
  float tot = red[0] + red[1] + red[2] + red[3];
  float rs = rsqrtf(tot + 1e-5f) * 32.0f;
  float4 g = ((const float4*)gamma)[threadIdx.x];
  bf16x4 o;
  o[0] = (__bf16)(v.x * rs * g.x);
  o[1] = (__bf16)(v.y * rs * g.y);
  o[2] = (__bf16)(v.z * rs * g.z);
  o[3] = (__bf16)(v.w * rs * g.w);
  *(bf16x4*)(h + (size_t)n * DIM + threadIdx.x * 4) = o;
}

// ---------------- 2-phase GEMM (wo split-K) --------------------------------
// 128x128 tile, BK=64, 4 waves 2x2, XCD bn-stripe swizzle; fp32 nontemporal
// partial to outf + blockIdx.z * SEQ*DIM.
__global__ __launch_bounds__(256) void gemm_bt_k(
    const __bf16* __restrict__ A, int lda,
    const __bf16* __restrict__ Bt, int ldb,
    float* __restrict__ outf, int ldc, int K) {
  __shared__ __bf16 lA[8192];
  __shared__ __bf16 lB[8192];
  const int t = threadIdx.x;
  const int lane = t & 63, wave = t >> 6;
  const int lo4 = lane & 15, hi2 = lane >> 4;
  const int nwg = gridDim.x * gridDim.y;
  const int orig = blockIdx.y * gridDim.x + blockIdx.x;   // hw dispatch id
  const int xcd = orig & 7, off = orig >> 3;
  const int qq = nwg >> 3, rr = nwg & 7;
  const int nid = (xcd < rr ? xcd * (qq + 1) : rr * (qq + 1) + (xcd - rr) * qq) + off;
  const int bm = nid % gridDim.y, bn = nid / gridDim.y;   // bm fastest
  const int k0 = blockIdx.z * K;
  const int wr = (wave >> 1) * 64, wc = (wave & 1) * 64;

  f32x4 acc[4][4];
#pragma unroll
  for (int m = 0; m < 4; m++)
#pragma unroll
    for (int n = 0; n < 4; n++) acc[m][n] = f32x4{0.f, 0.f, 0.f, 0.f};

  const int e0 = t * 8;
  const int e1 = 2048 + t * 8;
  const __bf16* gA0 = A + (size_t)(bm * 128 + (e0 >> 5)) * lda + (e0 & 31) + k0;
  const __bf16* gA1 = A + (size_t)(bm * 128 + (e1 >> 5)) * lda + (e1 & 31) + k0;
  const __bf16* gB0 = Bt + (size_t)(bn * 128 + (e0 >> 5)) * ldb + (e0 & 31) + k0;
  const __bf16* gB1 = Bt + (size_t)(bn * 128 + (e1 >> 5)) * ldb + (e1 & 31) + k0;
  __bf16* dA0 = &lA[wave * 512];
  __bf16* dA1 = &lA[2048 + wave * 512];
  __bf16* dB0 = &lB[wave * 512];
  __bf16* dB1 = &lB[2048 + wave * 512];

  for (int kt = 0; kt < K; kt += 64) {
    load_lds16(gA0 + kt, dA0);
    load_lds16(gA1 + kt, dA1);
    load_lds16(gB0 + kt, dB0);
    load_lds16(gB1 + kt, dB1);
    load_lds16(gA0 + kt + 32, dA0 + 4096);
    load_lds16(gA1 + kt + 32, dA1 + 4096);
    load_lds16(gB0 + kt + 32, dB0 + 4096);
    load_lds16(gB1 + kt + 32, dB1 + 4096);
    __syncthreads();
#pragma unroll
    for (int half = 0; half < 2; half++) {
      const __bf16* sA = &lA[half * 4096];
      const __bf16* sB = &lB[half * 4096];
      bf16x8 af[4], bf_[4];
#pragma unroll
      for (int m = 0; m < 4; m++)
        af[m] = *(const bf16x8*)&sA[(wr + m * 16 + lo4) * 32 + hi2 * 8];
#pragma unroll
      for (int n = 0; n < 4; n++)
        bf_[n] = *(const bf16x8*)&sB[(wc + n * 16 + lo4) * 32 + hi2 * 8];
#pragma unroll
      for (int m = 0; m < 4; m++)
#pragma unroll
        for (int n = 0; n < 4; n++)
          acc[m][n] = mfma16(af[m], bf_[n], acc[m][n]);
    }
    __syncthreads();
  }

  float* op = outf + (size_t)blockIdx.z * SEQ * DIM;   // split-K partial
#pragma unroll
  for (int m = 0; m < 4; m++) {
    const int rowb = bm * 128 + wr + m * 16 + hi2 * 4;
#pragma unroll
    for (int n = 0; n < 4; n++) {
      const int col = bn * 128 + wc + n * 16 + lo4;
#pragma unroll
      for (int j = 0; j < 4; j++)
        __builtin_nontemporal_store(acc[m][n][j], &op[(size_t)(rowb + j) * ldc + col]);
    }
  }
}

// ---------------- 256x256 8-phase GEMM (wi MODE 1, logits MODE 0) ----------
// A[M][K], Bt[N][K] row-major bf16.  K%128==0.  8 waves (2M x 4N), BK=64,
// K-tile-parity double buffer, st_16x32 swizzle via pre-swizzled global src.
// MODE 0: C fp32 nontemporal.  MODE 1 (wi, B = permuted wiT, 64-col wave
// quadrant quad = bn*4+wc): quad<17 -> q/k hi/lo split (col<1088);
// quad==17 -> v scatter to vT[64][SEQ]; 18<=quad<146 -> ff*swish(gate)->aof;
// quad>=146 -> pad, dropped.
template <int MODE>
__global__ __launch_bounds__(512, 1) void gemm256_k(
    const __bf16* __restrict__ A, const __bf16* __restrict__ Bt,
    float* __restrict__ C, int ldc,
    __bf16* __restrict__ qh, __bf16* __restrict__ ql,
    __bf16* __restrict__ vT, __bf16* __restrict__ aof,
    int K) {
  __shared__ __bf16 lds[65536];   // A: elems [0,32768), B: [32768,65536)
  const int t = threadIdx.x;
  const int lane = t & 63, w = t >> 6;
  const int lo4 = lane & 15, hi2 = lane >> 4;
  const int wr = w >> 2, wc = w & 3;       // 2 x 4 wave grid
  const int nwg = gridDim.x * gridDim.y;
  const int orig = blockIdx.y * gridDim.x + blockIdx.x;
  const int xcd = orig & 7, off = orig >> 3;
  const int qq = nwg >> 3, rr = nwg & 7;
  const int nid = (xcd < rr ? xcd * (qq + 1) : rr * (qq + 1) + (xcd - rr) * qq) + off;
  const int bm = nid % gridDim.y, bn = nid / gridDim.y;

  const int srow = lane >> 2;
  const int scol = ((lane & 3) * 8) ^ ((lane >> 5) << 4);   // pre-swizzled src
  const __bf16* gA = A + (size_t)(bm * 256 + srow) * K + scol;
  const __bf16* gB = Bt + (size_t)(bn * 256 + srow) * K + scol;
  const int cpr = (hi2 * 8) ^ ((lo4 >= 8) ? 16 : 0);        // read-side XOR

  auto STAGE = [&](int kt, int ks, int isB) {
    const __bf16* g = (isB ? gB : gA) + kt * 64 + ks * 32;
    __bf16* l = &lds[isB * 32768 + (kt & 1) * 16384 + ks * 8192 + (2 * w) * 512];
    load_lds16(g + (size_t)(2 * w) * 16 * K, l);
    load_lds16(g + (size_t)(2 * w + 1) * 16 * K, l + 512);
  };

  f32x4 acc[8][4];
#pragma unroll
  for (int m = 0; m < 8; m++)
#pragma unroll
    for (int n = 0; n < 4; n++) acc[m][n] = f32x4{0.f, 0.f, 0.f, 0.f};

  STAGE(0, 0, 0); STAGE(0, 0, 1); STAGE(0, 1, 0); STAGE(0, 1, 1);

  const int NIT = K >> 7;
  bf16x8 bfr[4];
  for (int it = 0; it < NIT; ++it) {
#pragma unroll
    for (int p = 0; p < 8; ++p) {
      const int g = p >> 2;
      const int u = p & 3;
      const int ks = u >> 1, mh = u & 1;
      const int kt = 2 * it + g;
      const bool dostage = (it < NIT - 1) || (g == 0);
      if ((u & 1) == 0) {
        if (it == NIT - 1 && g == 1 && u == 2)
          asm volatile("s_waitcnt vmcnt(0)" ::: "memory");
        else
          asm volatile("s_waitcnt vmcnt(4)" ::: "memory");
        __builtin_amdgcn_s_barrier();
      }
      const int abase = g * 16384 + ks * 8192 + lo4 * 32 + cpr;
      if ((u & 1) == 0) {
#pragma unroll
        for (int n = 0; n < 4; n++)
          bfr[n] = *(const bf16x8*)&lds[32768 + abase + (wc * 4 + n) * 512];
      }
      bf16x8 af[4];
#pragma unroll
      for (int mm = 0; mm < 4; mm++)
        af[mm] = *(const bf16x8*)&lds[abase + (wr * 8 + mh * 4 + mm) * 512];
      if (dostage) STAGE(kt + 1, ks, u & 1);
      __builtin_amdgcn_s_setprio(1);
#pragma unroll
      for (int mm = 0; mm < 4; mm++)
#pragma unroll
        for (int n = 0; n < 4; n++)
          acc[mh * 4 + mm][n] = mfma16(af[mm], bfr[n], acc[mh * 4 + mm][n]);
      __builtin_amdgcn_s_setprio(0);
    }
  }

  if (MODE == 0) {
#pragma unroll
    for (int m = 0; m < 8; m++) {
      const int rowb = bm * 256 + wr * 128 + m * 16 + hi2 * 4;
#pragma unroll
      for (int n = 0; n < 4; n++) {
        const int col = bn * 256 + wc * 64 + n * 16 + lo4;
#pragma unroll
        for (int j = 0; j < 4; j++)
          __builtin_nontemporal_store(acc[m][n][j], &C[(size_t)(rowb + j) * ldc + col]);
      }
    }
  } else {
    const int quad = bn * 4 + wc;           // global 64-col quadrant
    if (quad < 17) {
      // q (quads 0..15) and k (quad 16): cols < 1088, hi/lo split
#pragma unroll
      for (int m = 0; m < 8; m++) {
        const int rowb = bm * 256 + wr * 128 + m * 16 + hi2 * 4;
#pragma unroll
        for (int n = 0; n < 4; n++) {
          const int col = quad * 64 + n * 16 + lo4;
#pragma unroll
          for (int j = 0; j < 4; j++) {
            float v = acc[m][n][j];
            __bf16 hi = (__bf16)v;
            qh[(size_t)(rowb + j) * QKW + col] = hi;
            ql[(size_t)(rowb + j) * QKW + col] = (__bf16)(v - (float)hi);
          }
        }
      }
    } else if (quad == 17) {
      // v (cols 1088..1151): transpose scatter to vT[64][SEQ]
#pragma unroll
      for (int m = 0; m < 8; m++) {
        const int rowb = bm * 256 + wr * 128 + m * 16 + hi2 * 4;
#pragma unroll
        for (int n = 0; n < 4; n++) {
          const int vcol = n * 16 + lo4;
#pragma unroll
          for (int j = 0; j < 4; j++)
            vT[(size_t)vcol * SEQ + rowb + j] = (__bf16)acc[m][n][j];
        }
      }
    } else if (quad < 146) {
      // interleaved ff/gate: even n = ff, odd n = gate, same lane.
#pragma unroll
      for (int m = 0; m < 8; m++) {
        const int rowb = bm * 256 + wr * 128 + m * 16 + hi2 * 4;
#pragma unroll
        for (int np = 0; np < 4; np += 2) {
          const int cb = quad * 64 - 1152 + np * 16;
          const int acol = 1024 + ((cb >> 5) << 4) + lo4;
#pragma unroll
          for (int j = 0; j < 4; j++) {
            float ff = acc[m][np][j];
            float gg = acc[m][np + 1][j];
            float s = gg / (1.f + expf(-gg));
            aof[(size_t)(rowb + j) * AFW + acol] = (__bf16)(ff * s);
          }
        }
      }
    }
    // quad >= 146: padding columns, dropped.
  }
}

// ---------------- flash attention (MQA, causal + ALiBi-on-j) ---------------
// 1024 blocks x 4 waves.  Each block: head h = b&15, chunk pair (s, 127-s).
// Wave pair (pr) splits the KV range of chunk c; LDS LSE merge at end.
__global__ __launch_bounds__(256, 4) void flash_k(
    const __bf16* __restrict__ qh, const __bf16* __restrict__ ql,
    const __bf16* __restrict__ vT, __bf16* __restrict__ aof) {
  const int t = threadIdx.x;
  const int lane = t & 63, wave = t >> 6;
  const int lo4 = lane & 15, hi2 = lane >> 4;
  const int b = blockIdx.x;
  const int h = b & 15;
  const int s = b >> 4;                     // 0..63
  const int pr = wave >> 1, half = wave & 1;
  const int c = pr ? (127 - s) : s;         // q-chunk 0..127
  const int qrow0 = c * 16;
  const int nt = (c >> 2) + 1;
  const int ntA = (nt + 1) >> 1;
  const int jt0 = half ? ntA : 0;
  const int jtE = half ? nt : ntA;
  const float slope2 = exp2f(-0.5f * (float)(h + 1)) * LOG2E;
  const float scale2 = 0.125f * LOG2E;

  __shared__ __bf16 lP[4][16][72];          // per-wave P tile
  __shared__ float smO[2][2][16][65];       // [pair][half][row][col] O halves
  __shared__ float sml[2][2][16][2];        // [pair][half][row][{m,l}]
  __bf16 (*lPw)[72] = lP[wave];

  bf16x8 qhf[2], qlf[2];
#pragma unroll
  for (int kk = 0; kk < 2; kk++) {
    size_t qoff = (size_t)(qrow0 + lo4) * QKW + h * 64 + kk * 32 + hi2 * 8;
    qhf[kk] = *(const bf16x8*)(qh + qoff);
    qlf[kk] = *(const bf16x8*)(ql + qoff);
  }

  float jb[4][4];
#pragma unroll
  for (int f = 0; f < 4; f++)
#pragma unroll
    for (int r = 0; r < 4; r++)
      jb[f][r] = slope2 * (float)(jt0 * 64 + f * 16 + hi2 * 4 + r);
  const float dj = slope2 * 64.0f;
  const int iq = qrow0 + lo4;

  f32x4 O[4];
#pragma unroll
  for (int f = 0; f < 4; f++) O[f] = f32x4{0.f, 0.f, 0.f, 0.f};
  float mr = -1e30f, lr = 0.f;

  for (int jt = jt0; jt < jtE; ++jt) {
    f32x4 sc[4];
#pragma unroll
    for (int f = 0; f < 4; f++) sc[f] = f32x4{0.f, 0.f, 0.f, 0.f};
    __builtin_amdgcn_s_setprio(1);
#pragma unroll
    for (int kk = 0; kk < 2; kk++) {
#pragma unroll
      for (int f = 0; f < 4; f++) {
        size_t koff = (size_t)(jt * 64 + f * 16 + lo4) * QKW + 1024 + kk * 32 + hi2 * 8;
        bf16x8 khf = *(const bf16x8*)(qh + koff);
        bf16x8 klf = *(const bf16x8*)(ql + koff);
        sc[f] = mfma16(khf, qlf[kk], sc[f]);
        sc[f] = mfma16(klf, qhf[kk], sc[f]);
        sc[f] = mfma16(khf, qhf[kk], sc[f]);
      }
    }
    __builtin_amdgcn_s_setprio(0);

    float pv[4][4];
    float tmax = -1e30f;
#pragma unroll
    for (int f = 0; f < 4; f++)
#pragma unroll
      for (int r = 0; r < 4; r++) {
        const int j = jt * 64 + f * 16 + hi2 * 4 + r;
        float v = fmaf(sc[f][r], scale2, jb[f][r]);
        if (j > iq) v = -1e30f;
        pv[f][r] = v;
        tmax = fmaxf(tmax, v);
      }
    tmax = fmaxf(tmax, __shfl_xor(tmax, 16, 64));
    tmax = fmaxf(tmax, __shfl_xor(tmax, 32, 64));
    float mn = fmaxf(mr, tmax);
    float corr = exp2f(mr - mn);
    mr = mn;
    float rs = 0.f;
#pragma unroll
    for (int f = 0; f < 4; f++)
#pragma unroll
      for (int r = 0; r < 4; r++) {
        float pe = exp2f(pv[f][r] - mn);
        __bf16 pb = (__bf16)pe;
        lPw[lo4][f * 16 + hi2 * 4 + r] = pb;
        rs += (float)pb;
      }
    rs += __shfl_xor(rs, 16, 64);
    rs += __shfl_xor(rs, 32, 64);
    lr = lr * corr + rs;
    float co[4];
#pragma unroll
    for (int r = 0; r < 4; r++)
      co[r] = __shfl(corr, (lane & 48) + hi2 * 4 + r, 64);
#pragma unroll
    for (int f = 0; f < 4; f++)
#pragma unroll
      for (int r = 0; r < 4; r++) O[f][r] *= co[r];

    __builtin_amdgcn_s_setprio(1);
#pragma unroll
    for (int kk = 0; kk < 2; kk++) {
      bf16x8 pa = *(const bf16x8*)&lPw[lo4][kk * 32 + hi2 * 8];
#pragma unroll
      for (int f = 0; f < 4; f++) {
        bf16x8 vb = *(const bf16x8*)(vT + (size_t)(f * 16 + lo4) * SEQ + jt * 64 + kk * 32 + hi2 * 8);
        O[f] = mfma16(pa, vb, O[f]);
      }
    }
    __builtin_amdgcn_s_setprio(0);

#pragma unroll
    for (int f = 0; f < 4; f++)
#pragma unroll
      for (int r = 0; r < 4; r++) jb[f][r] += dj;
  }

  // ---- merge the two KV-halves via LDS ----
#pragma unroll
  for (int f = 0; f < 4; f++)
#pragma unroll
    for (int r = 0; r < 4; r++)
      smO[pr][half][hi2 * 4 + r][f * 16 + lo4] = O[f][r];
  if (hi2 == 0) {
    sml[pr][half][lo4][0] = mr;
    sml[pr][half][lo4][1] = lr;
  }
  __syncthreads();
  if (half == 0) {
#pragma unroll
    for (int r = 0; r < 4; r++) {
      const int row = hi2 * 4 + r;
      float mA = sml[pr][0][row][0], lA = sml[pr][0][row][1];
      float mB = sml[pr][1][row][0], lB = sml[pr][1][row][1];
      float mS = fmaxf(mA, mB);
      float cA = exp2f(mA - mS), cB = exp2f(mB - mS);
      float li = lA * cA + lB * cB;
#pragma unroll
      for (int f = 0; f < 4; f++) {
        float v = (smO[pr][0][row][f * 16 + lo4] * cA +
                   smO[pr][1][row][f * 16 + lo4] * cB) / li;
        aof[(size_t)(qrow0 + row) * AFW + h * 64 + f * 16 + lo4] = (__bf16)v;
      }
    }
  }
}

// ---------------------------------------------------------------------------

extern "C" void kernel_launch(void* const* d_in, const int* in_sizes, int n_in,
                              void* d_out, int out_size, void* d_ws, size_t ws_size,
                              hipStream_t stream) {
  const int* tokens  = (const int*)d_in[0];
  const float* emb   = (const float*)d_in[1];
  const float* wi    = (const float*)d_in[2];
  const float* awo   = (const float*)d_in[3];
  const float* fwo   = (const float*)d_in[4];
  const float* gam   = (const float*)d_in[5];
  const float* fgam  = (const float*)d_in[6];
  float* out = (float*)d_out;

  char* wsp = (char*)d_ws;
  size_t woff = 0;
  auto walloc = [&](size_t b) { void* p = wsp + woff; woff += (b + 255) & ~(size_t)255; return p; };
  __bf16* embb = (__bf16*)walloc((size_t)VOCAB * DIM * 2);
  __bf16* h    = (__bf16*)walloc((size_t)SEQ * DIM * 2);

  char* op = (char*)d_out;
  size_t ooff = 0;
  auto oalloc = [&](size_t b) { void* p = op + ooff; ooff += (b + 255) & ~(size_t)255; return p; };
  float*  xA    = (float*)oalloc((size_t)SEQ * DIM * 4);
  float*  xB    = (float*)oalloc((size_t)SEQ * DIM * 4);
  float*  pp    = (float*)oalloc((size_t)2 * SEQ * DIM * 4);  // split-K partials
  __bf16* qhb   = (__bf16*)oalloc((size_t)SEQ * QKW * 2);
  __bf16* qlb   = (__bf16*)oalloc((size_t)SEQ * QKW * 2);
  __bf16* vT    = (__bf16*)oalloc((size_t)DHEAD * SEQ * 2);
  __bf16* aof   = (__bf16*)oalloc((size_t)SEQ * AFW * 2);
  __bf16* wiT4  = (__bf16*)oalloc((size_t)4 * WIN * DIM * 2);   // 77.6 MB
  __bf16* BT24  = (__bf16*)oalloc((size_t)4 * DIM * AFW * 2);   // 41.9 MB
  (void)ws_size; (void)in_sizes; (void)n_in; (void)out_size;

  cast_k<<<(VOCAB * DIM / 8 + 255) / 256, 256, 0, stream>>>(emb, embb, VOCAB * DIM / 8);
  // batched weight prep (all layers, hoisted)
  transpose_wi_k<<<dim3(FUSEN / 64, DIM / 64, 4), 256, 0, stream>>>(wi, wiT4);
  transpose_b_k<<<dim3(DIM / 64, DIM / 64, 4), 256, 0, stream>>>(
      awo, BT24, DIM, DIM, AFW, 0, (size_t)DIM * AFW);
  transpose_b_k<<<dim3(DIM / 64, FFIN / 64, 4), 256, 0, stream>>>(
      fwo, BT24, FFIN, DIM, AFW, 1024, (size_t)DIM * AFW);

  float* x = xA;
  float* xn = xB;
  for (int l = 0; l < 4; l++) {
    if (l == 0) {
      // gather + rmsnorm fused: writes x (=xA) and h
      rmsnorm_fuse_k<0><<<SEQ, 256, 0, stream>>>(
          nullptr, nullptr, tokens, emb, gam, x, h);
    } else {
      rmsnorm_fuse_k<1><<<SEQ, 256, 0, stream>>>(
          x, pp, nullptr, nullptr, gam + l * DIM, xn, h);
      float* tmp = x; x = xn; xn = tmp;
    }
    gemm256_k<1><<<dim3(WIN / 256, SEQ / 256), 512, 0, stream>>>(
        h, wiT4 + (size_t)l * WIN * DIM, nullptr, 0, qhb, qlb, vT, aof, DIM);
    flash_k<<<dim3(1024), 256, 0, stream>>>(qhb, qlb, vT, aof);
    gemm_bt_k<<<dim3(DIM / 128, SEQ / 128, 2), 256, 0, stream>>>(
        aof, AFW, BT24 + (size_t)l * DIM * AFW, AFW, pp, DIM, AFW / 2);
  }

  rmsnorm_fuse_k<2><<<SEQ, 256, 0, stream>>>(
      x, pp, nullptr, nullptr, fgam, nullptr, h);
  gemm256_k<0><<<dim3(VOCAB / 256, SEQ / 256), 512, 0, stream>>>(
      h, embb, out, VOCAB, nullptr, nullptr, nullptr, nullptr, DIM);
}

// Round 15
// 1134.626 us; speedup vs baseline: 1.0634x; 1.0634x over previous
//
#include <hip/hip_runtime.h>
#include <stdint.h>

// ---------------------------------------------------------------------------
// PaLM forward (DEPTH=4, DIM=1024, HEADS=16 MQA, DIM_HEAD=64, SEQ=2048,
// VOCAB=32000).  bf16 MFMA GEMMs (fp32 accum), fp32 residual stream,
// split-bf16 (hi+lo) QK^T.  Logits: 256x256 8-phase (counted vmcnt +
// st_16x32 swizzle + setprio; only wins at nwg>>256).  wi: 2-phase 128^2
// with FUSED epilogue (q/k hi-lo split, v->vT scatter, ff*swish(gate)->aof).
// wo: 2-phase split-K=4 partials (2 blocks/CU) merged in fused
// residual+rmsnorm.  Flash: wave-pair KV-split (round-11 measured-best).
// ---------------------------------------------------------------------------

typedef __attribute__((ext_vector_type(8))) __bf16 bf16x8;
typedef __attribute__((ext_vector_type(4))) __bf16 bf16x4;
typedef __attribute__((ext_vector_type(8))) short s16x8;
typedef __attribute__((ext_vector_type(4))) float f32x4;

#define SEQ   2048
#define DIM   1024
#define NHEAD 16
#define DHEAD 64
#define FUSEN 9344   // 1024 q + 64 k + 64 v + 4096 ff + 4096 gate
#define QKW   1088   // q+k columns -> hi/lo bf16 pair (precise attention)
#define FFIN  4096
#define VOCAB 32000
#define AFW   5120   // merged activation width: ao(1024) | ffact(4096)
#define LOG2E 1.44269504f

__device__ __forceinline__ f32x4 mfma16(bf16x8 a, bf16x8 b, f32x4 c) {
  return __builtin_amdgcn_mfma_f32_16x16x32_bf16(
      __builtin_bit_cast(s16x8, a), __builtin_bit_cast(s16x8, b), c, 0, 0, 0);
}

__device__ __forceinline__ void load_lds16(const __bf16* g, __bf16* l) {
  __builtin_amdgcn_global_load_lds(
      (const __attribute__((address_space(1))) uint32_t*)g,
      (__attribute__((address_space(3))) uint32_t*)l, 16, 0, 0);
}

// ---------------- elementwise / prep kernels -------------------------------

__global__ void cast_k(const float* __restrict__ in, __bf16* __restrict__ out, int n8) {
  int i = blockIdx.x * 256 + threadIdx.x;
  if (i >= n8) return;
  const float4* p = (const float4*)in + (size_t)i * 2;
  float4 a = p[0], b = p[1];
  bf16x8 o;
  o[0] = (__bf16)a.x; o[1] = (__bf16)a.y; o[2] = (__bf16)a.z; o[3] = (__bf16)a.w;
  o[4] = (__bf16)b.x; o[5] = (__bf16)b.y; o[6] = (__bf16)b.z; o[7] = (__bf16)b.w;
  *(bf16x8*)(out + (size_t)i * 8) = o;
}

// ff/gate interleave permutation for wiT rows (dst row for source col c):
// q/k/v (c<1152) unchanged; ff i -> 1152+32*(i/16)+(i%16); gate i -> +16.
__device__ __forceinline__ int permcol(int c) {
  if (c < 1152) return c;
  if (c < 5248) { int i = c - 1152; return 1152 + ((i >> 4) << 5) + (i & 15); }
  int i = c - 5248; return 1152 + ((i >> 4) << 5) + 16 + (i & 15);
}

// batched: wi [L][DIM][FUSEN] fp32 -> wiT4 [L][perm(FUSEN)][DIM] bf16.
// 64x64 tiles: 256B-contiguous reads, 128B-contiguous bf16 writes.
__global__ __launch_bounds__(256) void transpose_wi_k(
    const float* __restrict__ in, __bf16* __restrict__ out) {
  __shared__ float tile[64][65];
  int l = blockIdx.z;
  int tx = threadIdx.x & 63, ty = threadIdx.x >> 6;   // 64 x 4
  int c0 = blockIdx.x * 64, r0 = blockIdx.y * 64;
  const float* inl = in + (size_t)l * DIM * FUSEN;
  __bf16* outl = out + (size_t)l * FUSEN * DIM;
  for (int i = ty; i < 64; i += 4)
    tile[i][tx] = inl[(size_t)(r0 + i) * FUSEN + c0 + tx];
  __syncthreads();
  for (int i = ty; i < 64; i += 4)
    outl[(size_t)permcol(c0 + i) * DIM + r0 + tx] = (__bf16)tile[tx][i];
}

// batched generic: in [L][R][C] fp32 -> out [L][C][ldo] bf16 at col offset co.
__global__ __launch_bounds__(256) void transpose_b_k(
    const float* __restrict__ in, __bf16* __restrict__ out,
    int R, int C, int ldo, int co, size_t outLstride) {
  __shared__ float tile[64][65];
  int l = blockIdx.z;
  int tx = threadIdx.x & 63, ty = threadIdx.x >> 6;
  int c0 = blockIdx.x * 64, r0 = blockIdx.y * 64;
  const float* inl = in + (size_t)l * R * C;
  __bf16* outl = out + (size_t)l * outLstride;
  for (int i = ty; i < 64; i += 4)
    tile[i][tx] = inl[(size_t)(r0 + i) * C + c0 + tx];
  __syncthreads();
  for (int i = ty; i < 64; i += 4)
    outl[(size_t)(c0 + i) * ldo + co + r0 + tx] = (__bf16)tile[tx][i];
}

// fused (gather|residual) + rmsnorm.
// MODE 0: v = emb[tokens[n]]; write xn = v.
// MODE 1: v = x + p0 + p1 + p2 + p3 (p = [4][SEQ][DIM]); write xn = v.
// MODE 2: same sum; no xn write (final norm).
template <int MODE>
__global__ __launch_bounds__(256) void rmsnorm_fuse_k(
    const float* __restrict__ x, const float* __restrict__ p,
    const int* __restrict__ tokens, const float* __restrict__ emb,
    const float* __restrict__ gamma, float* __restrict__ xn,
    __bf16* __restrict__ h) {
  int n = blockIdx.x;
  float4 v;
  if (MODE == 0) {
    int tok = tokens[n];
    v = ((const float4*)(emb + (size_t)tok * DIM))[threadIdx.x];
    ((float4*)(xn + (size_t)n * DIM))[threadIdx.x] = v;
  } else {
    v = ((const float4*)(x + (size_t)n * DIM))[threadIdx.x];
#pragma unroll
    for (int z = 0; z < 4; z++) {
      float4 a = ((const float4*)(p + (size_t)(z * SEQ + n) * DIM))[threadIdx.x];
      v.x += a.x; v.y += a.y; v.z += a.z; v.w += a.w;
    }
    if (MODE == 1)
      ((float4*)(xn + (size_t)n * DIM))[threadIdx.x] = v;
  }
  float ssq = v.x * v.x + v.y * v.y + v.z * v.z + v.w * v.w;
  for (int m = 32; m >= 1; m >>= 1) ssq += __shfl_xor(ssq, m, 64);
  __shared__ float red[4];
  if ((threadIdx.x & 63) == 0) red[threadIdx.x >> 6] = ssq;
  __syncthreads();
  float tot = red[0] + red[1] + red[2] + red[3];
  float rs = rsqrtf(tot + 1e-5f) * 32.0f;
  float4 g = ((const float4*)gamma)[threadIdx.x];
  bf16x4 o;
  o[0] = (__bf16)(v.x * rs * g.x);
  o[1] = (__bf16)(v.y * rs * g.y);
  o[2] = (__bf16)(v.z * rs * g.z);
  o[3] = (__bf16)(v.w * rs * g.w);
  *(bf16x4*)(h + (size_t)n * DIM + threadIdx.x * 4) = o;
}

// ---------------- 2-phase GEMM (wi MODE 1, wo split-K MODE 0) --------------
// 128x128 tile, BK=64, 4 waves 2x2, XCD bn-stripe swizzle.
// MODE 0: fp32 nontemporal to outf + blockIdx.z * SEQ*DIM (split-K partial).
// MODE 1 (wi, B = permuted wiT): bn<8 or (bn==8,wc==0) -> q/k hi/lo split;
//   bn==8,wc==64 -> v scatter to vT[64][SEQ]; bn>=9 -> ff*swish(gate) -> aof.
template <int MODE>
__global__ __launch_bounds__(256) void gemm_bt_k(
    const __bf16* __restrict__ A, int lda,
    const __bf16* __restrict__ Bt, int ldb,
    float* __restrict__ outf, int ldc,
    __bf16* __restrict__ qh, __bf16* __restrict__ ql,
    __bf16* __restrict__ vT, __bf16* __restrict__ aof,
    int K) {
  __shared__ __bf16 lA[8192];
  __shared__ __bf16 lB[8192];
  const int t = threadIdx.x;
  const int lane = t & 63, wave = t >> 6;
  const int lo4 = lane & 15, hi2 = lane >> 4;
  const int nwg = gridDim.x * gridDim.y;
  const int orig = blockIdx.y * gridDim.x + blockIdx.x;   // hw dispatch id
  const int xcd = orig & 7, off = orig >> 3;
  const int qq = nwg >> 3, rr = nwg & 7;
  const int nid = (xcd < rr ? xcd * (qq + 1) : rr * (qq + 1) + (xcd - rr) * qq) + off;
  const int bm = nid % gridDim.y, bn = nid / gridDim.y;   // bm fastest
  const int k0 = blockIdx.z * K;
  const int wr = (wave >> 1) * 64, wc = (wave & 1) * 64;

  f32x4 acc[4][4];
#pragma unroll
  for (int m = 0; m < 4; m++)
#pragma unroll
    for (int n = 0; n < 4; n++) acc[m][n] = f32x4{0.f, 0.f, 0.f, 0.f};

  const int e0 = t * 8;
  const int e1 = 2048 + t * 8;
  const __bf16* gA0 = A + (size_t)(bm * 128 + (e0 >> 5)) * lda + (e0 & 31) + k0;
  const __bf16* gA1 = A + (size_t)(bm * 128 + (e1 >> 5)) * lda + (e1 & 31) + k0;
  const __bf16* gB0 = Bt + (size_t)(bn * 128 + (e0 >> 5)) * ldb + (e0 & 31) + k0;
  const __bf16* gB1 = Bt + (size_t)(bn * 128 + (e1 >> 5)) * ldb + (e1 & 31) + k0;
  __bf16* dA0 = &lA[wave * 512];
  __bf16* dA1 = &lA[2048 + wave * 512];
  __bf16* dB0 = &lB[wave * 512];
  __bf16* dB1 = &lB[2048 + wave * 512];

  for (int kt = 0; kt < K; kt += 64) {
    load_lds16(gA0 + kt, dA0);
    load_lds16(gA1 + kt, dA1);
    load_lds16(gB0 + kt, dB0);
    load_lds16(gB1 + kt, dB1);
    load_lds16(gA0 + kt + 32, dA0 + 4096);
    load_lds16(gA1 + kt + 32, dA1 + 4096);
    load_lds16(gB0 + kt + 32, dB0 + 4096);
    load_lds16(gB1 + kt + 32, dB1 + 4096);
    __syncthreads();
#pragma unroll
    for (int half = 0; half < 2; half++) {
      const __bf16* sA = &lA[half * 4096];
      const __bf16* sB = &lB[half * 4096];
      bf16x8 af[4], bf_[4];
#pragma unroll
      for (int m = 0; m < 4; m++)
        af[m] = *(const bf16x8*)&sA[(wr + m * 16 + lo4) * 32 + hi2 * 8];
#pragma unroll
      for (int n = 0; n < 4; n++)
        bf_[n] = *(const bf16x8*)&sB[(wc + n * 16 + lo4) * 32 + hi2 * 8];
#pragma unroll
      for (int m = 0; m < 4; m++)
#pragma unroll
        for (int n = 0; n < 4; n++)
          acc[m][n] = mfma16(af[m], bf_[n], acc[m][n]);
    }
    __syncthreads();
  }

  if (MODE == 0) {
    float* op = outf + (size_t)blockIdx.z * SEQ * DIM;   // split-K partial
#pragma unroll
    for (int m = 0; m < 4; m++) {
      const int rowb = bm * 128 + wr + m * 16 + hi2 * 4;
#pragma unroll
      for (int n = 0; n < 4; n++) {
        const int col = bn * 128 + wc + n * 16 + lo4;
#pragma unroll
        for (int j = 0; j < 4; j++)
          __builtin_nontemporal_store(acc[m][n][j], &op[(size_t)(rowb + j) * ldc + col]);
      }
    }
  } else if (bn < 8 || (bn == 8 && wc == 0)) {
    // q (bn<8) and k (bn==8, cols 1024..1087): hi/lo split
#pragma unroll
    for (int m = 0; m < 4; m++) {
      const int rowb = bm * 128 + wr + m * 16 + hi2 * 4;
#pragma unroll
      for (int n = 0; n < 4; n++) {
        const int col = bn * 128 + wc + n * 16 + lo4;
#pragma unroll
        for (int j = 0; j < 4; j++) {
          float v = acc[m][n][j];
          __bf16 hi = (__bf16)v;
          qh[(size_t)(rowb + j) * QKW + col] = hi;
          ql[(size_t)(rowb + j) * QKW + col] = (__bf16)(v - (float)hi);
        }
      }
    }
  } else if (bn == 8) {
    // v (cols 1088..1151): direct transpose scatter to vT[64][SEQ]
#pragma unroll
    for (int m = 0; m < 4; m++) {
      const int rowb = bm * 128 + wr + m * 16 + hi2 * 4;
#pragma unroll
      for (int n = 0; n < 4; n++) {
        const int vcol = n * 16 + lo4;   // wc==64: col-1088 = n*16+lo4
#pragma unroll
        for (int j = 0; j < 4; j++)
          vT[(size_t)vcol * SEQ + rowb + j] = (__bf16)acc[m][n][j];
      }
    }
  } else {
    // interleaved ff/gate (bn>=9): even n = ff, odd n = gate, same lane.
#pragma unroll
    for (int m = 0; m < 4; m++) {
      const int rowb = bm * 128 + wr + m * 16 + hi2 * 4;
#pragma unroll
      for (int np = 0; np < 4; np += 2) {
        const int cb = (bn - 9) * 128 + wc + np * 16;      // (col-1152) base
        const int acol = 1024 + ((cb >> 5) << 4) + lo4;
#pragma unroll
        for (int j = 0; j < 4; j++) {
          float ff = acc[m][np][j];
          float gg = acc[m][np + 1][j];
          float s = gg / (1.f + expf(-gg));
          aof[(size_t)(rowb + j) * AFW + acol] = (__bf16)(ff * s);
        }
      }
    }
  }
}

// ---------------- 256x256 8-phase GEMM (logits) ----------------------------
__global__ __launch_bounds__(512, 1) void gemm256_k(
    const __bf16* __restrict__ A, const __bf16* __restrict__ Bt,
    float* __restrict__ C, int ldc, int K) {
  __shared__ __bf16 lds[65536];   // A: elems [0,32768), B: [32768,65536)
  const int t = threadIdx.x;
  const int lane = t & 63, w = t >> 6;
  const int lo4 = lane & 15, hi2 = lane >> 4;
  const int wr = w >> 2, wc = w & 3;       // 2 x 4 wave grid
  const int nwg = gridDim.x * gridDim.y;
  const int orig = blockIdx.y * gridDim.x + blockIdx.x;
  const int xcd = orig & 7, off = orig >> 3;
  const int qq = nwg >> 3, rr = nwg & 7;
  const int nid = (xcd < rr ? xcd * (qq + 1) : rr * (qq + 1) + (xcd - rr) * qq) + off;
  const int bm = nid % gridDim.y, bn = nid / gridDim.y;

  const int srow = lane >> 2;
  const int scol = ((lane & 3) * 8) ^ ((lane >> 5) << 4);   // pre-swizzled src
  const __bf16* gA = A + (size_t)(bm * 256 + srow) * K + scol;
  const __bf16* gB = Bt + (size_t)(bn * 256 + srow) * K + scol;
  const int cpr = (hi2 * 8) ^ ((lo4 >= 8) ? 16 : 0);        // read-side XOR

  auto STAGE = [&](int kt, int ks, int isB) {
    const __bf16* g = (isB ? gB : gA) + kt * 64 + ks * 32;
    __bf16* l = &lds[isB * 32768 + (kt & 1) * 16384 + ks * 8192 + (2 * w) * 512];
    load_lds16(g + (size_t)(2 * w) * 16 * K, l);
    load_lds16(g + (size_t)(2 * w + 1) * 16 * K, l + 512);
  };

  f32x4 acc[8][4];
#pragma unroll
  for (int m = 0; m < 8; m++)
#pragma unroll
    for (int n = 0; n < 4; n++) acc[m][n] = f32x4{0.f, 0.f, 0.f, 0.f};

  STAGE(0, 0, 0); STAGE(0, 0, 1); STAGE(0, 1, 0); STAGE(0, 1, 1);

  const int NIT = K >> 7;
  bf16x8 bfr[4];
  for (int it = 0; it < NIT; ++it) {
#pragma unroll
    for (int p = 0; p < 8; ++p) {
      const int g = p >> 2;
      const int u = p & 3;
      const int ks = u >> 1, mh = u & 1;
      const int kt = 2 * it + g;
      const bool dostage = (it < NIT - 1) || (g == 0);
      if ((u & 1) == 0) {
        if (it == NIT - 1 && g == 1 && u == 2)
          asm volatile("s_waitcnt vmcnt(0)" ::: "memory");
        else
          asm volatile("s_waitcnt vmcnt(4)" ::: "memory");
        __builtin_amdgcn_s_barrier();
      }
      const int abase = g * 16384 + ks * 8192 + lo4 * 32 + cpr;
      if ((u & 1) == 0) {
#pragma unroll
        for (int n = 0; n < 4; n++)
          bfr[n] = *(const bf16x8*)&lds[32768 + abase + (wc * 4 + n) * 512];
      }
      bf16x8 af[4];
#pragma unroll
      for (int mm = 0; mm < 4; mm++)
        af[mm] = *(const bf16x8*)&lds[abase + (wr * 8 + mh * 4 + mm) * 512];
      if (dostage) STAGE(kt + 1, ks, u & 1);
      __builtin_amdgcn_s_setprio(1);
#pragma unroll
      for (int mm = 0; mm < 4; mm++)
#pragma unroll
        for (int n = 0; n < 4; n++)
          acc[mh * 4 + mm][n] = mfma16(af[mm], bfr[n], acc[mh * 4 + mm][n]);
      __builtin_amdgcn_s_setprio(0);
    }
  }

#pragma unroll
  for (int m = 0; m < 8; m++) {
    const int rowb = bm * 256 + wr * 128 + m * 16 + hi2 * 4;
#pragma unroll
    for (int n = 0; n < 4; n++) {
      const int col = bn * 256 + wc * 64 + n * 16 + lo4;
#pragma unroll
      for (int j = 0; j < 4; j++)
        __builtin_nontemporal_store(acc[m][n][j], &C[(size_t)(rowb + j) * ldc + col]);
    }
  }
}

// ---------------- flash attention (MQA, causal + ALiBi-on-j) ---------------
// 1024 blocks x 4 waves.  Each block: head h = b&15, chunk pair (s, 127-s).
// Wave pair (pr) splits the KV range of chunk c; LDS LSE merge at end.
__global__ __launch_bounds__(256, 4) void flash_k(
    const __bf16* __restrict__ qh, const __bf16* __restrict__ ql,
    const __bf16* __restrict__ vT, __bf16* __restrict__ aof) {
  const int t = threadIdx.x;
  const int lane = t & 63, wave = t >> 6;
  const int lo4 = lane & 15, hi2 = lane >> 4;
  const int b = blockIdx.x;
  const int h = b & 15;
  const int s = b >> 4;                     // 0..63
  const int pr = wave >> 1, half = wave & 1;
  const int c = pr ? (127 - s) : s;         // q-chunk 0..127
  const int qrow0 = c * 16;
  const int nt = (c >> 2) + 1;
  const int ntA = (nt + 1) >> 1;
  const int jt0 = half ? ntA : 0;
  const int jtE = half ? nt : ntA;
  const float slope2 = exp2f(-0.5f * (float)(h + 1)) * LOG2E;
  const float scale2 = 0.125f * LOG2E;

  __shared__ __bf16 lP[4][16][72];          // per-wave P tile
  __shared__ float smO[2][2][16][65];       // [pair][half][row][col] O halves
  __shared__ float sml[2][2][16][2];        // [pair][half][row][{m,l}]
  __bf16 (*lPw)[72] = lP[wave];

  bf16x8 qhf[2], qlf[2];
#pragma unroll
  for (int kk = 0; kk < 2; kk++) {
    size_t qoff = (size_t)(qrow0 + lo4) * QKW + h * 64 + kk * 32 + hi2 * 8;
    qhf[kk] = *(const bf16x8*)(qh + qoff);
    qlf[kk] = *(const bf16x8*)(ql + qoff);
  }

  float jb[4][4];
#pragma unroll
  for (int f = 0; f < 4; f++)
#pragma unroll
    for (int r = 0; r < 4; r++)
      jb[f][r] = slope2 * (float)(jt0 * 64 + f * 16 + hi2 * 4 + r);
  const float dj = slope2 * 64.0f;
  const int iq = qrow0 + lo4;

  f32x4 O[4];
#pragma unroll
  for (int f = 0; f < 4; f++) O[f] = f32x4{0.f, 0.f, 0.f, 0.f};
  float mr = -1e30f, lr = 0.f;

  for (int jt = jt0; jt < jtE; ++jt) {
    f32x4 sc[4];
#pragma unroll
    for (int f = 0; f < 4; f++) sc[f] = f32x4{0.f, 0.f, 0.f, 0.f};
    __builtin_amdgcn_s_setprio(1);
#pragma unroll
    for (int kk = 0; kk < 2; kk++) {
#pragma unroll
      for (int f = 0; f < 4; f++) {
        size_t koff = (size_t)(jt * 64 + f * 16 + lo4) * QKW + 1024 + kk * 32 + hi2 * 8;
        bf16x8 khf = *(const bf16x8*)(qh + koff);
        bf16x8 klf = *(const bf16x8*)(ql + koff);
        sc[f] = mfma16(khf, qlf[kk], sc[f]);
        sc[f] = mfma16(klf, qhf[kk], sc[f]);
        sc[f] = mfma16(khf, qhf[kk], sc[f]);
      }
    }
    __builtin_amdgcn_s_setprio(0);

    float pv[4][4];
    float tmax = -1e30f;
#pragma unroll
    for (int f = 0; f < 4; f++)
#pragma unroll
      for (int r = 0; r < 4; r++) {
        const int j = jt * 64 + f * 16 + hi2 * 4 + r;
        float v = fmaf(sc[f][r], scale2, jb[f][r]);
        if (j > iq) v = -1e30f;
        pv[f][r] = v;
        tmax = fmaxf(tmax, v);
      }
    tmax = fmaxf(tmax, __shfl_xor(tmax, 16, 64));
    tmax = fmaxf(tmax, __shfl_xor(tmax, 32, 64));
    float mn = fmaxf(mr, tmax);
    float corr = exp2f(mr - mn);
    mr = mn;
    float rs = 0.f;
#pragma unroll
    for (int f = 0; f < 4; f++)
#pragma unroll
      for (int r = 0; r < 4; r++) {
        float pe = exp2f(pv[f][r] - mn);
        __bf16 pb = (__bf16)pe;
        lPw[lo4][f * 16 + hi2 * 4 + r] = pb;
        rs += (float)pb;
      }
    rs += __shfl_xor(rs, 16, 64);
    rs += __shfl_xor(rs, 32, 64);
    lr = lr * corr + rs;
    float co[4];
#pragma unroll
    for (int r = 0; r < 4; r++)
      co[r] = __shfl(corr, (lane & 48) + hi2 * 4 + r, 64);
#pragma unroll
    for (int f = 0; f < 4; f++)
#pragma unroll
      for (int r = 0; r < 4; r++) O[f][r] *= co[r];

    __builtin_amdgcn_s_setprio(1);
#pragma unroll
    for (int kk = 0; kk < 2; kk++) {
      bf16x8 pa = *(const bf16x8*)&lPw[lo4][kk * 32 + hi2 * 8];
#pragma unroll
      for (int f = 0; f < 4; f++) {
        bf16x8 vb = *(const bf16x8*)(vT + (size_t)(f * 16 + lo4) * SEQ + jt * 64 + kk * 32 + hi2 * 8);
        O[f] = mfma16(pa, vb, O[f]);
      }
    }
    __builtin_amdgcn_s_setprio(0);

#pragma unroll
    for (int f = 0; f < 4; f++)
#pragma unroll
      for (int r = 0; r < 4; r++) jb[f][r] += dj;
  }

  // ---- merge the two KV-halves via LDS ----
#pragma unroll
  for (int f = 0; f < 4; f++)
#pragma unroll
    for (int r = 0; r < 4; r++)
      smO[pr][half][hi2 * 4 + r][f * 16 + lo4] = O[f][r];
  if (hi2 == 0) {
    sml[pr][half][lo4][0] = mr;
    sml[pr][half][lo4][1] = lr;
  }
  __syncthreads();
  if (half == 0) {
#pragma unroll
    for (int r = 0; r < 4; r++) {
      const int row = hi2 * 4 + r;
      float mA = sml[pr][0][row][0], lA = sml[pr][0][row][1];
      float mB = sml[pr][1][row][0], lB = sml[pr][1][row][1];
      float mS = fmaxf(mA, mB);
      float cA = exp2f(mA - mS), cB = exp2f(mB - mS);
      float li = lA * cA + lB * cB;
#pragma unroll
      for (int f = 0; f < 4; f++) {
        float v = (smO[pr][0][row][f * 16 + lo4] * cA +
                   smO[pr][1][row][f * 16 + lo4] * cB) / li;
        aof[(size_t)(qrow0 + row) * AFW + h * 64 + f * 16 + lo4] = (__bf16)v;
      }
    }
  }
}

// ---------------------------------------------------------------------------

extern "C" void kernel_launch(void* const* d_in, const int* in_sizes, int n_in,
                              void* d_out, int out_size, void* d_ws, size_t ws_size,
                              hipStream_t stream) {
  const int* tokens  = (const int*)d_in[0];
  const float* emb   = (const float*)d_in[1];
  const float* wi    = (const float*)d_in[2];
  const float* awo   = (const float*)d_in[3];
  const float* fwo   = (const float*)d_in[4];
  const float* gam   = (const float*)d_in[5];
  const float* fgam  = (const float*)d_in[6];
  float* out = (float*)d_out;

  char* wsp = (char*)d_ws;
  size_t woff = 0;
  auto walloc = [&](size_t b) { void* p = wsp + woff; woff += (b + 255) & ~(size_t)255; return p; };
  __bf16* embb = (__bf16*)walloc((size_t)VOCAB * DIM * 2);
  __bf16* h    = (__bf16*)walloc((size_t)SEQ * DIM * 2);

  char* op = (char*)d_out;
  size_t ooff = 0;
  auto oalloc = [&](size_t b) { void* p = op + ooff; ooff += (b + 255) & ~(size_t)255; return p; };
  float*  xA    = (float*)oalloc((size_t)SEQ * DIM * 4);
  float*  xB    = (float*)oalloc((size_t)SEQ * DIM * 4);
  float*  pp    = (float*)oalloc((size_t)4 * SEQ * DIM * 4);  // split-K partials
  __bf16* qhb   = (__bf16*)oalloc((size_t)SEQ * QKW * 2);
  __bf16* qlb   = (__bf16*)oalloc((size_t)SEQ * QKW * 2);
  __bf16* vT    = (__bf16*)oalloc((size_t)DHEAD * SEQ * 2);
  __bf16* aof   = (__bf16*)oalloc((size_t)SEQ * AFW * 2);
  __bf16* wiT4  = (__bf16*)oalloc((size_t)4 * FUSEN * DIM * 2);  // 76.6 MB
  __bf16* BT24  = (__bf16*)oalloc((size_t)4 * DIM * AFW * 2);    // 41.9 MB
  (void)ws_size; (void)in_sizes; (void)n_in; (void)out_size;

  cast_k<<<(VOCAB * DIM / 8 + 255) / 256, 256, 0, stream>>>(emb, embb, VOCAB * DIM / 8);
  // batched weight prep (all layers, hoisted)
  transpose_wi_k<<<dim3(FUSEN / 64, DIM / 64, 4), 256, 0, stream>>>(wi, wiT4);
  transpose_b_k<<<dim3(DIM / 64, DIM / 64, 4), 256, 0, stream>>>(
      awo, BT24, DIM, DIM, AFW, 0, (size_t)DIM * AFW);
  transpose_b_k<<<dim3(DIM / 64, FFIN / 64, 4), 256, 0, stream>>>(
      fwo, BT24, FFIN, DIM, AFW, 1024, (size_t)DIM * AFW);

  float* x = xA;
  float* xn = xB;
  for (int l = 0; l < 4; l++) {
    if (l == 0) {
      // gather + rmsnorm fused: writes x (=xA) and h
      rmsnorm_fuse_k<0><<<SEQ, 256, 0, stream>>>(
          nullptr, nullptr, tokens, emb, gam, x, h);
    } else {
      rmsnorm_fuse_k<1><<<SEQ, 256, 0, stream>>>(
          x, pp, nullptr, nullptr, gam + l * DIM, xn, h);
      float* tmp = x; x = xn; xn = tmp;
    }
    gemm_bt_k<1><<<dim3(FUSEN / 128, SEQ / 128), 256, 0, stream>>>(
        h, DIM, wiT4 + (size_t)l * FUSEN * DIM, DIM, nullptr, 0,
        qhb, qlb, vT, aof, DIM);
    flash_k<<<dim3(1024), 256, 0, stream>>>(qhb, qlb, vT, aof);
    gemm_bt_k<0><<<dim3(DIM / 128, SEQ / 128, 4), 256, 0, stream>>>(
        aof, AFW, BT24 + (size_t)l * DIM * AFW, AFW, pp, DIM,
        nullptr, nullptr, nullptr, nullptr, AFW / 4);
  }

  rmsnorm_fuse_k<2><<<SEQ, 256, 0, stream>>>(
      x, pp, nullptr, nullptr, fgam, nullptr, h);
  gemm256_k<<<dim3(VOCAB / 256, SEQ / 256), 512, 0, stream>>>(
      h, embb, out, VOCAB, DIM);
}

// Round 16
// 1120.238 us; speedup vs baseline: 1.0771x; 1.0128x over previous
//
#include <hip/hip_runtime.h>
#include <stdint.h>

// ---------------------------------------------------------------------------
// PaLM forward (DEPTH=4, DIM=1024, HEADS=16 MQA, DIM_HEAD=64, SEQ=2048,
// VOCAB=32000).  bf16 MFMA GEMMs (fp32 accum), fp32 residual stream,
// split-bf16 (hi+lo) QK^T.  Logits: 256x256 8-phase (counted vmcnt +
// st_16x32 swizzle + setprio) with LDS-repacked full-line C stores.
// wi: 2-phase 128^2 with FUSED epilogue (q/k hi-lo split, v->vT scatter,
// ff*swish(gate)->aof).  wo: 2-phase split-K=4 partials merged in fused
// residual+rmsnorm.  Flash: wave-pair KV-split (round-11 measured-best).
// ---------------------------------------------------------------------------

typedef __attribute__((ext_vector_type(8))) __bf16 bf16x8;
typedef __attribute__((ext_vector_type(4))) __bf16 bf16x4;
typedef __attribute__((ext_vector_type(8))) short s16x8;
typedef __attribute__((ext_vector_type(4))) float f32x4;

#define SEQ   2048
#define DIM   1024
#define NHEAD 16
#define DHEAD 64
#define FUSEN 9344   // 1024 q + 64 k + 64 v + 4096 ff + 4096 gate
#define QKW   1088   // q+k columns -> hi/lo bf16 pair (precise attention)
#define FFIN  4096
#define VOCAB 32000
#define AFW   5120   // merged activation width: ao(1024) | ffact(4096)
#define LOG2E 1.44269504f

__device__ __forceinline__ f32x4 mfma16(bf16x8 a, bf16x8 b, f32x4 c) {
  return __builtin_amdgcn_mfma_f32_16x16x32_bf16(
      __builtin_bit_cast(s16x8, a), __builtin_bit_cast(s16x8, b), c, 0, 0, 0);
}

__device__ __forceinline__ void load_lds16(const __bf16* g, __bf16* l) {
  __builtin_amdgcn_global_load_lds(
      (const __attribute__((address_space(1))) uint32_t*)g,
      (__attribute__((address_space(3))) uint32_t*)l, 16, 0, 0);
}

// ---------------- elementwise / prep kernels -------------------------------

__global__ void cast_k(const float* __restrict__ in, __bf16* __restrict__ out, int n8) {
  int i = blockIdx.x * 256 + threadIdx.x;
  if (i >= n8) return;
  const float4* p = (const float4*)in + (size_t)i * 2;
  float4 a = p[0], b = p[1];
  bf16x8 o;
  o[0] = (__bf16)a.x; o[1] = (__bf16)a.y; o[2] = (__bf16)a.z; o[3] = (__bf16)a.w;
  o[4] = (__bf16)b.x; o[5] = (__bf16)b.y; o[6] = (__bf16)b.z; o[7] = (__bf16)b.w;
  *(bf16x8*)(out + (size_t)i * 8) = o;
}

// ff/gate interleave permutation for wiT rows (dst row for source col c):
// q/k/v (c<1152) unchanged; ff i -> 1152+32*(i/16)+(i%16); gate i -> +16.
__device__ __forceinline__ int permcol(int c) {
  if (c < 1152) return c;
  if (c < 5248) { int i = c - 1152; return 1152 + ((i >> 4) << 5) + (i & 15); }
  int i = c - 5248; return 1152 + ((i >> 4) << 5) + 16 + (i & 15);
}

// batched: wi [L][DIM][FUSEN] fp32 -> wiT4 [L][perm(FUSEN)][DIM] bf16.
__global__ __launch_bounds__(256) void transpose_wi_k(
    const float* __restrict__ in, __bf16* __restrict__ out) {
  __shared__ float tile[64][65];
  int l = blockIdx.z;
  int tx = threadIdx.x & 63, ty = threadIdx.x >> 6;   // 64 x 4
  int c0 = blockIdx.x * 64, r0 = blockIdx.y * 64;
  const float* inl = in + (size_t)l * DIM * FUSEN;
  __bf16* outl = out + (size_t)l * FUSEN * DIM;
  for (int i = ty; i < 64; i += 4)
    tile[i][tx] = inl[(size_t)(r0 + i) * FUSEN + c0 + tx];
  __syncthreads();
  for (int i = ty; i < 64; i += 4)
    outl[(size_t)permcol(c0 + i) * DIM + r0 + tx] = (__bf16)tile[tx][i];
}

// batched generic: in [L][R][C] fp32 -> out [L][C][ldo] bf16 at col offset co.
__global__ __launch_bounds__(256) void transpose_b_k(
    const float* __restrict__ in, __bf16* __restrict__ out,
    int R, int C, int ldo, int co, size_t outLstride) {
  __shared__ float tile[64][65];
  int l = blockIdx.z;
  int tx = threadIdx.x & 63, ty = threadIdx.x >> 6;
  int c0 = blockIdx.x * 64, r0 = blockIdx.y * 64;
  const float* inl = in + (size_t)l * R * C;
  __bf16* outl = out + (size_t)l * outLstride;
  for (int i = ty; i < 64; i += 4)
    tile[i][tx] = inl[(size_t)(r0 + i) * C + c0 + tx];
  __syncthreads();
  for (int i = ty; i < 64; i += 4)
    outl[(size_t)(c0 + i) * ldo + co + r0 + tx] = (__bf16)tile[tx][i];
}

// fused (gather|residual) + rmsnorm.
// MODE 0: v = emb[tokens[n]]; write xn = v.
// MODE 1: v = x + p0 + p1 + p2 + p3 (p = [4][SEQ][DIM]); write xn = v.
// MODE 2: same sum; no xn write (final norm).
template <int MODE>
__global__ __launch_bounds__(256) void rmsnorm_fuse_k(
    const float* __restrict__ x, const float* __restrict__ p,
    const int* __restrict__ tokens, const float* __restrict__ emb,
    const float* __restrict__ gamma, float* __restrict__ xn,
    __bf16* __restrict__ h) {
  int n = blockIdx.x;
  float4 v;
  if (MODE == 0) {
    int tok = tokens[n];
    v = ((const float4*)(emb + (size_t)tok * DIM))[threadIdx.x];
    ((float4*)(xn + (size_t)n * DIM))[threadIdx.x] = v;
  } else {
    v = ((const float4*)(x + (size_t)n * DIM))[threadIdx.x];
#pragma unroll
    for (int z = 0; z < 4; z++) {
      float4 a = ((const float4*)(p + (size_t)(z * SEQ + n) * DIM))[threadIdx.x];
      v.x += a.x; v.y += a.y; v.z += a.z; v.w += a.w;
    }
    if (MODE == 1)
      ((float4*)(xn + (size_t)n * DIM))[threadIdx.x] = v;
  }
  float ssq = v.x * v.x + v.y * v.y + v.z * v.z + v.w * v.w;
  for (int m = 32; m >= 1; m >>= 1) ssq += __shfl_xor(ssq, m, 64);
  __shared__ float red[4];
  if ((threadIdx.x & 63) == 0) red[threadIdx.x >> 6] = ssq;
  __syncthreads();
  float tot = red[0] + red[1] + red[2] + red[3];
  float rs = rsqrtf(tot + 1e-5f) * 32.0f;
  float4 g = ((const float4*)gamma)[threadIdx.x];
  bf16x4 o;
  o[0] = (__bf16)(v.x * rs * g.x);
  o[1] = (__bf16)(v.y * rs * g.y);
  o[2] = (__bf16)(v.z * rs * g.z);
  o[3] = (__bf16)(v.w * rs * g.w);
  *(bf16x4*)(h + (size_t)n * DIM + threadIdx.x * 4) = o;
}

// ---------------- 2-phase GEMM (wi MODE 1, wo split-K MODE 0) --------------
// 128x128 tile, BK=64, 4 waves 2x2, XCD bn-stripe swizzle.
// MODE 0: fp32 nontemporal to outf + blockIdx.z * SEQ*DIM (split-K partial).
// MODE 1 (wi, B = permuted wiT): bn<8 or (bn==8,wc==0) -> q/k hi/lo split;
//   bn==8,wc==64 -> v scatter to vT[64][SEQ]; bn>=9 -> ff*swish(gate) -> aof.
template <int MODE>
__global__ __launch_bounds__(256) void gemm_bt_k(
    const __bf16* __restrict__ A, int lda,
    const __bf16* __restrict__ Bt, int ldb,
    float* __restrict__ outf, int ldc,
    __bf16* __restrict__ qh, __bf16* __restrict__ ql,
    __bf16* __restrict__ vT, __bf16* __restrict__ aof,
    int K) {
  __shared__ __bf16 lA[8192];
  __shared__ __bf16 lB[8192];
  const int t = threadIdx.x;
  const int lane = t & 63, wave = t >> 6;
  const int lo4 = lane & 15, hi2 = lane >> 4;
  const int nwg = gridDim.x * gridDim.y;
  const int orig = blockIdx.y * gridDim.x + blockIdx.x;   // hw dispatch id
  const int xcd = orig & 7, off = orig >> 3;
  const int qq = nwg >> 3, rr = nwg & 7;
  const int nid = (xcd < rr ? xcd * (qq + 1) : rr * (qq + 1) + (xcd - rr) * qq) + off;
  const int bm = nid % gridDim.y, bn = nid / gridDim.y;   // bm fastest
  const int k0 = blockIdx.z * K;
  const int wr = (wave >> 1) * 64, wc = (wave & 1) * 64;

  f32x4 acc[4][4];
#pragma unroll
  for (int m = 0; m < 4; m++)
#pragma unroll
    for (int n = 0; n < 4; n++) acc[m][n] = f32x4{0.f, 0.f, 0.f, 0.f};

  const int e0 = t * 8;
  const int e1 = 2048 + t * 8;
  const __bf16* gA0 = A + (size_t)(bm * 128 + (e0 >> 5)) * lda + (e0 & 31) + k0;
  const __bf16* gA1 = A + (size_t)(bm * 128 + (e1 >> 5)) * lda + (e1 & 31) + k0;
  const __bf16* gB0 = Bt + (size_t)(bn * 128 + (e0 >> 5)) * ldb + (e0 & 31) + k0;
  const __bf16* gB1 = Bt + (size_t)(bn * 128 + (e1 >> 5)) * ldb + (e1 & 31) + k0;
  __bf16* dA0 = &lA[wave * 512];
  __bf16* dA1 = &lA[2048 + wave * 512];
  __bf16* dB0 = &lB[wave * 512];
  __bf16* dB1 = &lB[2048 + wave * 512];

  for (int kt = 0; kt < K; kt += 64) {
    load_lds16(gA0 + kt, dA0);
    load_lds16(gA1 + kt, dA1);
    load_lds16(gB0 + kt, dB0);
    load_lds16(gB1 + kt, dB1);
    load_lds16(gA0 + kt + 32, dA0 + 4096);
    load_lds16(gA1 + kt + 32, dA1 + 4096);
    load_lds16(gB0 + kt + 32, dB0 + 4096);
    load_lds16(gB1 + kt + 32, dB1 + 4096);
    __syncthreads();
#pragma unroll
    for (int half = 0; half < 2; half++) {
      const __bf16* sA = &lA[half * 4096];
      const __bf16* sB = &lB[half * 4096];
      bf16x8 af[4], bf_[4];
#pragma unroll
      for (int m = 0; m < 4; m++)
        af[m] = *(const bf16x8*)&sA[(wr + m * 16 + lo4) * 32 + hi2 * 8];
#pragma unroll
      for (int n = 0; n < 4; n++)
        bf_[n] = *(const bf16x8*)&sB[(wc + n * 16 + lo4) * 32 + hi2 * 8];
#pragma unroll
      for (int m = 0; m < 4; m++)
#pragma unroll
        for (int n = 0; n < 4; n++)
          acc[m][n] = mfma16(af[m], bf_[n], acc[m][n]);
    }
    __syncthreads();
  }

  if (MODE == 0) {
    float* op = outf + (size_t)blockIdx.z * SEQ * DIM;   // split-K partial
#pragma unroll
    for (int m = 0; m < 4; m++) {
      const int rowb = bm * 128 + wr + m * 16 + hi2 * 4;
#pragma unroll
      for (int n = 0; n < 4; n++) {
        const int col = bn * 128 + wc + n * 16 + lo4;
#pragma unroll
        for (int j = 0; j < 4; j++)
          __builtin_nontemporal_store(acc[m][n][j], &op[(size_t)(rowb + j) * ldc + col]);
      }
    }
  } else if (bn < 8 || (bn == 8 && wc == 0)) {
    // q (bn<8) and k (bn==8, cols 1024..1087): hi/lo split
#pragma unroll
    for (int m = 0; m < 4; m++) {
      const int rowb = bm * 128 + wr + m * 16 + hi2 * 4;
#pragma unroll
      for (int n = 0; n < 4; n++) {
        const int col = bn * 128 + wc + n * 16 + lo4;
#pragma unroll
        for (int j = 0; j < 4; j++) {
          float v = acc[m][n][j];
          __bf16 hi = (__bf16)v;
          qh[(size_t)(rowb + j) * QKW + col] = hi;
          ql[(size_t)(rowb + j) * QKW + col] = (__bf16)(v - (float)hi);
        }
      }
    }
  } else if (bn == 8) {
    // v (cols 1088..1151): direct transpose scatter to vT[64][SEQ]
#pragma unroll
    for (int m = 0; m < 4; m++) {
      const int rowb = bm * 128 + wr + m * 16 + hi2 * 4;
#pragma unroll
      for (int n = 0; n < 4; n++) {
        const int vcol = n * 16 + lo4;   // wc==64: col-1088 = n*16+lo4
#pragma unroll
        for (int j = 0; j < 4; j++)
          vT[(size_t)vcol * SEQ + rowb + j] = (__bf16)acc[m][n][j];
      }
    }
  } else {
    // interleaved ff/gate (bn>=9): even n = ff, odd n = gate, same lane.
#pragma unroll
    for (int m = 0; m < 4; m++) {
      const int rowb = bm * 128 + wr + m * 16 + hi2 * 4;
#pragma unroll
      for (int np = 0; np < 4; np += 2) {
        const int cb = (bn - 9) * 128 + wc + np * 16;      // (col-1152) base
        const int acol = 1024 + ((cb >> 5) << 4) + lo4;
#pragma unroll
        for (int j = 0; j < 4; j++) {
          float ff = acc[m][np][j];
          float gg = acc[m][np + 1][j];
          float s = gg / (1.f + expf(-gg));
          aof[(size_t)(rowb + j) * AFW + acol] = (__bf16)(ff * s);
        }
      }
    }
  }
}

// ---------------- 256x256 8-phase GEMM (logits) ----------------------------
// LDS-repacked epilogue: stage each 128-row half as fp32 [128][256] in LDS,
// then stream full-cache-line float4 nontemporal stores (1KB-contiguous
// rows), eliminating 64B partial-line write bursts.
__global__ __launch_bounds__(512, 1) void gemm256_k(
    const __bf16* __restrict__ A, const __bf16* __restrict__ Bt,
    float* __restrict__ C, int ldc, int K) {
  __shared__ __bf16 lds[65536];   // A: elems [0,32768), B: [32768,65536)
  const int t = threadIdx.x;
  const int lane = t & 63, w = t >> 6;
  const int lo4 = lane & 15, hi2 = lane >> 4;
  const int wr = w >> 2, wc = w & 3;       // 2 x 4 wave grid
  const int nwg = gridDim.x * gridDim.y;
  const int orig = blockIdx.y * gridDim.x + blockIdx.x;
  const int xcd = orig & 7, off = orig >> 3;
  const int qq = nwg >> 3, rr = nwg & 7;
  const int nid = (xcd < rr ? xcd * (qq + 1) : rr * (qq + 1) + (xcd - rr) * qq) + off;
  const int bm = nid % gridDim.y, bn = nid / gridDim.y;

  const int srow = lane >> 2;
  const int scol = ((lane & 3) * 8) ^ ((lane >> 5) << 4);   // pre-swizzled src
  const __bf16* gA = A + (size_t)(bm * 256 + srow) * K + scol;
  const __bf16* gB = Bt + (size_t)(bn * 256 + srow) * K + scol;
  const int cpr = (hi2 * 8) ^ ((lo4 >= 8) ? 16 : 0);        // read-side XOR

  auto STAGE = [&](int kt, int ks, int isB) {
    const __bf16* g = (isB ? gB : gA) + kt * 64 + ks * 32;
    __bf16* l = &lds[isB * 32768 + (kt & 1) * 16384 + ks * 8192 + (2 * w) * 512];
    load_lds16(g + (size_t)(2 * w) * 16 * K, l);
    load_lds16(g + (size_t)(2 * w + 1) * 16 * K, l + 512);
  };

  f32x4 acc[8][4];
#pragma unroll
  for (int m = 0; m < 8; m++)
#pragma unroll
    for (int n = 0; n < 4; n++) acc[m][n] = f32x4{0.f, 0.f, 0.f, 0.f};

  STAGE(0, 0, 0); STAGE(0, 0, 1); STAGE(0, 1, 0); STAGE(0, 1, 1);

  const int NIT = K >> 7;
  bf16x8 bfr[4];
  for (int it = 0; it < NIT; ++it) {
#pragma unroll
    for (int p = 0; p < 8; ++p) {
      const int g = p >> 2;
      const int u = p & 3;
      const int ks = u >> 1, mh = u & 1;
      const int kt = 2 * it + g;
      const bool dostage = (it < NIT - 1) || (g == 0);
      if ((u & 1) == 0) {
        if (it == NIT - 1 && g == 1 && u == 2)
          asm volatile("s_waitcnt vmcnt(0)" ::: "memory");
        else
          asm volatile("s_waitcnt vmcnt(4)" ::: "memory");
        __builtin_amdgcn_s_barrier();
      }
      const int abase = g * 16384 + ks * 8192 + lo4 * 32 + cpr;
      if ((u & 1) == 0) {
#pragma unroll
        for (int n = 0; n < 4; n++)
          bfr[n] = *(const bf16x8*)&lds[32768 + abase + (wc * 4 + n) * 512];
      }
      bf16x8 af[4];
#pragma unroll
      for (int mm = 0; mm < 4; mm++)
        af[mm] = *(const bf16x8*)&lds[abase + (wr * 8 + mh * 4 + mm) * 512];
      if (dostage) STAGE(kt + 1, ks, u & 1);
      __builtin_amdgcn_s_setprio(1);
#pragma unroll
      for (int mm = 0; mm < 4; mm++)
#pragma unroll
        for (int n = 0; n < 4; n++)
          acc[mh * 4 + mm][n] = mfma16(af[mm], bfr[n], acc[mh * 4 + mm][n]);
      __builtin_amdgcn_s_setprio(0);
    }
  }

  // ---- epilogue: repack -> LDS fp32 [128][256] per half, wide stores ----
  float* lf = (float*)lds;
#pragma unroll
  for (int half = 0; half < 2; half++) {
    __builtin_amdgcn_s_barrier();     // protects main-loop LDS / prev chunk
    if (wr == half) {
#pragma unroll
      for (int m = 0; m < 8; m++) {
        const int r = m * 16 + hi2 * 4;
#pragma unroll
        for (int n = 0; n < 4; n++) {
          const int cc = wc * 64 + n * 16 + lo4;
#pragma unroll
          for (int j = 0; j < 4; j++)
            lf[(r + j) * 256 + cc] = acc[m][n][j];
        }
      }
    }
    __builtin_amdgcn_s_barrier();
    const int rowbase = bm * 256 + half * 128;
    const int colbase = bn * 256;
#pragma unroll
    for (int itq = 0; itq < 16; itq++) {
      const int f = (itq * 512 + t) * 4;   // flat float index in [128][256]
      const int r = f >> 8;
      const int cc = f & 255;
      f32x4 v4 = *(const f32x4*)&lf[f];
      __builtin_nontemporal_store(
          v4, (f32x4*)&C[(size_t)(rowbase + r) * ldc + colbase + cc]);
    }
  }
}

// ---------------- flash attention (MQA, causal + ALiBi-on-j) ---------------
// 1024 blocks x 4 waves.  Each block: head h = b&15, chunk pair (s, 127-s).
// Wave pair (pr) splits the KV range of chunk c; LDS LSE merge at end.
__global__ __launch_bounds__(256, 4) void flash_k(
    const __bf16* __restrict__ qh, const __bf16* __restrict__ ql,
    const __bf16* __restrict__ vT, __bf16* __restrict__ aof) {
  const int t = threadIdx.x;
  const int lane = t & 63, wave = t >> 6;
  const int lo4 = lane & 15, hi2 = lane >> 4;
  const int b = blockIdx.x;
  const int h = b & 15;
  const int s = b >> 4;                     // 0..63
  const int pr = wave >> 1, half = wave & 1;
  const int c = pr ? (127 - s) : s;         // q-chunk 0..127
  const int qrow0 = c * 16;
  const int nt = (c >> 2) + 1;
  const int ntA = (nt + 1) >> 1;
  const int jt0 = half ? ntA : 0;
  const int jtE = half ? nt : ntA;
  const float slope2 = exp2f(-0.5f * (float)(h + 1)) * LOG2E;
  const float scale2 = 0.125f * LOG2E;

  __shared__ __bf16 lP[4][16][72];          // per-wave P tile
  __shared__ float smO[2][2][16][65];       // [pair][half][row][col] O halves
  __shared__ float sml[2][2][16][2];        // [pair][half][row][{m,l}]
  __bf16 (*lPw)[72] = lP[wave];

  bf16x8 qhf[2], qlf[2];
#pragma unroll
  for (int kk = 0; kk < 2; kk++) {
    size_t qoff = (size_t)(qrow0 + lo4) * QKW + h * 64 + kk * 32 + hi2 * 8;
    qhf[kk] = *(const bf16x8*)(qh + qoff);
    qlf[kk] = *(const bf16x8*)(ql + qoff);
  }

  float jb[4][4];
#pragma unroll
  for (int f = 0; f < 4; f++)
#pragma unroll
    for (int r = 0; r < 4; r++)
      jb[f][r] = slope2 * (float)(jt0 * 64 + f * 16 + hi2 * 4 + r);
  const float dj = slope2 * 64.0f;
  const int iq = qrow0 + lo4;

  f32x4 O[4];
#pragma unroll
  for (int f = 0; f < 4; f++) O[f] = f32x4{0.f, 0.f, 0.f, 0.f};
  float mr = -1e30f, lr = 0.f;

  for (int jt = jt0; jt < jtE; ++jt) {
    f32x4 sc[4];
#pragma unroll
    for (int f = 0; f < 4; f++) sc[f] = f32x4{0.f, 0.f, 0.f, 0.f};
    __builtin_amdgcn_s_setprio(1);
#pragma unroll
    for (int kk = 0; kk < 2; kk++) {
#pragma unroll
      for (int f = 0; f < 4; f++) {
        size_t koff = (size_t)(jt * 64 + f * 16 + lo4) * QKW + 1024 + kk * 32 + hi2 * 8;
        bf16x8 khf = *(const bf16x8*)(qh + koff);
        bf16x8 klf = *(const bf16x8*)(ql + koff);
        sc[f] = mfma16(khf, qlf[kk], sc[f]);
        sc[f] = mfma16(klf, qhf[kk], sc[f]);
        sc[f] = mfma16(khf, qhf[kk], sc[f]);
      }
    }
    __builtin_amdgcn_s_setprio(0);

    float pv[4][4];
    float tmax = -1e30f;
#pragma unroll
    for (int f = 0; f < 4; f++)
#pragma unroll
      for (int r = 0; r < 4; r++) {
        const int j = jt * 64 + f * 16 + hi2 * 4 + r;
        float v = fmaf(sc[f][r], scale2, jb[f][r]);
        if (j > iq) v = -1e30f;
        pv[f][r] = v;
        tmax = fmaxf(tmax, v);
      }
    tmax = fmaxf(tmax, __shfl_xor(tmax, 16, 64));
    tmax = fmaxf(tmax, __shfl_xor(tmax, 32, 64));
    float mn = fmaxf(mr, tmax);
    float corr = exp2f(mr - mn);
    mr = mn;
    float rs = 0.f;
#pragma unroll
    for (int f = 0; f < 4; f++)
#pragma unroll
      for (int r = 0; r < 4; r++) {
        float pe = exp2f(pv[f][r] - mn);
        __bf16 pb = (__bf16)pe;
        lPw[lo4][f * 16 + hi2 * 4 + r] = pb;
        rs += (float)pb;
      }
    rs += __shfl_xor(rs, 16, 64);
    rs += __shfl_xor(rs, 32, 64);
    lr = lr * corr + rs;
    float co[4];
#pragma unroll
    for (int r = 0; r < 4; r++)
      co[r] = __shfl(corr, (lane & 48) + hi2 * 4 + r, 64);
#pragma unroll
    for (int f = 0; f < 4; f++)
#pragma unroll
      for (int r = 0; r < 4; r++) O[f][r] *= co[r];

    __builtin_amdgcn_s_setprio(1);
#pragma unroll
    for (int kk = 0; kk < 2; kk++) {
      bf16x8 pa = *(const bf16x8*)&lPw[lo4][kk * 32 + hi2 * 8];
#pragma unroll
      for (int f = 0; f < 4; f++) {
        bf16x8 vb = *(const bf16x8*)(vT + (size_t)(f * 16 + lo4) * SEQ + jt * 64 + kk * 32 + hi2 * 8);
        O[f] = mfma16(pa, vb, O[f]);
      }
    }
    __builtin_amdgcn_s_setprio(0);

#pragma unroll
    for (int f = 0; f < 4; f++)
#pragma unroll
      for (int r = 0; r < 4; r++) jb[f][r] += dj;
  }

  // ---- merge the two KV-halves via LDS ----
#pragma unroll
  for (int f = 0; f < 4; f++)
#pragma unroll
    for (int r = 0; r < 4; r++)
      smO[pr][half][hi2 * 4 + r][f * 16 + lo4] = O[f][r];
  if (hi2 == 0) {
    sml[pr][half][lo4][0] = mr;
    sml[pr][half][lo4][1] = lr;
  }
  __syncthreads();
  if (half == 0) {
#pragma unroll
    for (int r = 0; r < 4; r++) {
      const int row = hi2 * 4 + r;
      float mA = sml[pr][0][row][0], lA = sml[pr][0][row][1];
      float mB = sml[pr][1][row][0], lB = sml[pr][1][row][1];
      float mS = fmaxf(mA, mB);
      float cA = exp2f(mA - mS), cB = exp2f(mB - mS);
      float li = lA * cA + lB * cB;
#pragma unroll
      for (int f = 0; f < 4; f++) {
        float v = (smO[pr][0][row][f * 16 + lo4] * cA +
                   smO[pr][1][row][f * 16 + lo4] * cB) / li;
        aof[(size_t)(qrow0 + row) * AFW + h * 64 + f * 16 + lo4] = (__bf16)v;
      }
    }
  }
}

// ---------------------------------------------------------------------------

extern "C" void kernel_launch(void* const* d_in, const int* in_sizes, int n_in,
                              void* d_out, int out_size, void* d_ws, size_t ws_size,
                              hipStream_t stream) {
  const int* tokens  = (const int*)d_in[0];
  const float* emb   = (const float*)d_in[1];
  const float* wi    = (const float*)d_in[2];
  const float* awo   = (const float*)d_in[3];
  const float* fwo   = (const float*)d_in[4];
  const float* gam   = (const float*)d_in[5];
  const float* fgam  = (const float*)d_in[6];
  float* out = (float*)d_out;

  char* wsp = (char*)d_ws;
  size_t woff = 0;
  auto walloc = [&](size_t b) { void* p = wsp + woff; woff += (b + 255) & ~(size_t)255; return p; };
  __bf16* embb = (__bf16*)walloc((size_t)VOCAB * DIM * 2);
  __bf16* h    = (__bf16*)walloc((size_t)SEQ * DIM * 2);

  char* op = (char*)d_out;
  size_t ooff = 0;
  auto oalloc = [&](size_t b) { void* p = op + ooff; ooff += (b + 255) & ~(size_t)255; return p; };
  float*  xA    = (float*)oalloc((size_t)SEQ * DIM * 4);
  float*  xB    = (float*)oalloc((size_t)SEQ * DIM * 4);
  float*  pp    = (float*)oalloc((size_t)4 * SEQ * DIM * 4);  // split-K partials
  __bf16* qhb   = (__bf16*)oalloc((size_t)SEQ * QKW * 2);
  __bf16* qlb   = (__bf16*)oalloc((size_t)SEQ * QKW * 2);
  __bf16* vT    = (__bf16*)oalloc((size_t)DHEAD * SEQ * 2);
  __bf16* aof   = (__bf16*)oalloc((size_t)SEQ * AFW * 2);
  __bf16* wiT4  = (__bf16*)oalloc((size_t)4 * FUSEN * DIM * 2);  // 76.6 MB
  __bf16* BT24  = (__bf16*)oalloc((size_t)4 * DIM * AFW * 2);    // 41.9 MB
  (void)ws_size; (void)in_sizes; (void)n_in; (void)out_size;

  cast_k<<<(VOCAB * DIM / 8 + 255) / 256, 256, 0, stream>>>(emb, embb, VOCAB * DIM / 8);
  // batched weight prep (all layers, hoisted)
  transpose_wi_k<<<dim3(FUSEN / 64, DIM / 64, 4), 256, 0, stream>>>(wi, wiT4);
  transpose_b_k<<<dim3(DIM / 64, DIM / 64, 4), 256, 0, stream>>>(
      awo, BT24, DIM, DIM, AFW, 0, (size_t)DIM * AFW);
  transpose_b_k<<<dim3(DIM / 64, FFIN / 64, 4), 256, 0, stream>>>(
      fwo, BT24, FFIN, DIM, AFW, 1024, (size_t)DIM * AFW);

  float* x = xA;
  float* xn = xB;
  for (int l = 0; l < 4; l++) {
    if (l == 0) {
      // gather + rmsnorm fused: writes x (=xA) and h
      rmsnorm_fuse_k<0><<<SEQ, 256, 0, stream>>>(
          nullptr, nullptr, tokens, emb, gam, x, h);
    } else {
      rmsnorm_fuse_k<1><<<SEQ, 256, 0, stream>>>(
          x, pp, nullptr, nullptr, gam + l * DIM, xn, h);
      float* tmp = x; x = xn; xn = tmp;
    }
    gemm_bt_k<1><<<dim3(FUSEN / 128, SEQ / 128), 256, 0, stream>>>(
        h, DIM, wiT4 + (size_t)l * FUSEN * DIM, DIM, nullptr, 0,
        qhb, qlb, vT, aof, DIM);
    flash_k<<<dim3(1024), 256, 0, stream>>>(qhb, qlb, vT, aof);
    gemm_bt_k<0><<<dim3(DIM / 128, SEQ / 128, 4), 256, 0, stream>>>(
        aof, AFW, BT24 + (size_t)l * DIM * AFW, AFW, pp, DIM,
        nullptr, nullptr, nullptr, nullptr, AFW / 4);
  }

  rmsnorm_fuse_k<2><<<SEQ, 256, 0, stream>>>(
      x, pp, nullptr, nullptr, fgam, nullptr, h);
  gemm256_k<<<dim3(VOCAB / 256, SEQ / 256), 512, 0, stream>>>(
      h, embb, out, VOCAB, DIM);
}

// Round 19
// 1119.601 us; speedup vs baseline: 1.0777x; 1.0006x over previous
//
#include <hip/hip_runtime.h>
#include <stdint.h>

// ---------------------------------------------------------------------------
// PaLM forward (DEPTH=4, DIM=1024, HEADS=16 MQA, DIM_HEAD=64, SEQ=2048,
// VOCAB=32000).  bf16 MFMA GEMMs (fp32 accum), fp32 residual stream,
// split-bf16 (hi+lo) QK^T.  Logits: 256x256 8-phase with LDS-repacked
// full-line C stores.  wi: 2-phase 128^2 fused epilogue (q/k hi-lo split,
// v->vT scatter, ff*swish(gate)->aof with LDS-repacked full-line stores).
// wo: 2-phase split-K=4 partials (LDS-repacked full-line stores) merged in
// fused residual+rmsnorm.  Flash: wave-pair KV-split.
// Epilogue LDS hand-offs use __syncthreads() (raw s_barrier lacks the
// lgkmcnt(0) drain -> cross-SIMD LDS race; caught by round-18 tripwire).
// ---------------------------------------------------------------------------

typedef __attribute__((ext_vector_type(8))) __bf16 bf16x8;
typedef __attribute__((ext_vector_type(4))) __bf16 bf16x4;
typedef __attribute__((ext_vector_type(8))) short s16x8;
typedef __attribute__((ext_vector_type(4))) float f32x4;

#define SEQ   2048
#define DIM   1024
#define NHEAD 16
#define DHEAD 64
#define FUSEN 9344   // 1024 q + 64 k + 64 v + 4096 ff + 4096 gate
#define QKW   1088   // q+k columns -> hi/lo bf16 pair (precise attention)
#define FFIN  4096
#define VOCAB 32000
#define AFW   5120   // merged activation width: ao(1024) | ffact(4096)
#define LOG2E 1.44269504f

__device__ __forceinline__ f32x4 mfma16(bf16x8 a, bf16x8 b, f32x4 c) {
  return __builtin_amdgcn_mfma_f32_16x16x32_bf16(
      __builtin_bit_cast(s16x8, a), __builtin_bit_cast(s16x8, b), c, 0, 0, 0);
}

__device__ __forceinline__ void load_lds16(const __bf16* g, __bf16* l) {
  __builtin_amdgcn_global_load_lds(
      (const __attribute__((address_space(1))) uint32_t*)g,
      (__attribute__((address_space(3))) uint32_t*)l, 16, 0, 0);
}

// ---------------- elementwise / prep kernels -------------------------------

__global__ void cast_k(const float* __restrict__ in, __bf16* __restrict__ out, int n8) {
  int i = blockIdx.x * 256 + threadIdx.x;
  if (i >= n8) return;
  const float4* p = (const float4*)in + (size_t)i * 2;
  float4 a = p[0], b = p[1];
  bf16x8 o;
  o[0] = (__bf16)a.x; o[1] = (__bf16)a.y; o[2] = (__bf16)a.z; o[3] = (__bf16)a.w;
  o[4] = (__bf16)b.x; o[5] = (__bf16)b.y; o[6] = (__bf16)b.z; o[7] = (__bf16)b.w;
  *(bf16x8*)(out + (size_t)i * 8) = o;
}

// ff/gate interleave permutation for wiT rows (dst row for source col c):
// q/k/v (c<1152) unchanged; ff i -> 1152+32*(i/16)+(i%16); gate i -> +16.
__device__ __forceinline__ int permcol(int c) {
  if (c < 1152) return c;
  if (c < 5248) { int i = c - 1152; return 1152 + ((i >> 4) << 5) + (i & 15); }
  int i = c - 5248; return 1152 + ((i >> 4) << 5) + 16 + (i & 15);
}

// batched: wi [L][DIM][FUSEN] fp32 -> wiT4 [L][perm(FUSEN)][DIM] bf16.
__global__ __launch_bounds__(256) void transpose_wi_k(
    const float* __restrict__ in, __bf16* __restrict__ out) {
  __shared__ float tile[64][65];
  int l = blockIdx.z;
  int tx = threadIdx.x & 63, ty = threadIdx.x >> 6;   // 64 x 4
  int c0 = blockIdx.x * 64, r0 = blockIdx.y * 64;
  const float* inl = in + (size_t)l * DIM * FUSEN;
  __bf16* outl = out + (size_t)l * FUSEN * DIM;
  for (int i = ty; i < 64; i += 4)
    tile[i][tx] = inl[(size_t)(r0 + i) * FUSEN + c0 + tx];
  __syncthreads();
  for (int i = ty; i < 64; i += 4)
    outl[(size_t)permcol(c0 + i) * DIM + r0 + tx] = (__bf16)tile[tx][i];
}

// batched generic: in [L][R][C] fp32 -> out [L][C][ldo] bf16 at col offset co.
__global__ __launch_bounds__(256) void transpose_b_k(
    const float* __restrict__ in, __bf16* __restrict__ out,
    int R, int C, int ldo, int co, size_t outLstride) {
  __shared__ float tile[64][65];
  int l = blockIdx.z;
  int tx = threadIdx.x & 63, ty = threadIdx.x >> 6;
  int c0 = blockIdx.x * 64, r0 = blockIdx.y * 64;
  const float* inl = in + (size_t)l * R * C;
  __bf16* outl = out + (size_t)l * outLstride;
  for (int i = ty; i < 64; i += 4)
    tile[i][tx] = inl[(size_t)(r0 + i) * C + c0 + tx];
  __syncthreads();
  for (int i = ty; i < 64; i += 4)
    outl[(size_t)(c0 + i) * ldo + co + r0 + tx] = (__bf16)tile[tx][i];
}

// fused (gather|residual) + rmsnorm.
// MODE 0: v = emb[tokens[n]]; write xn = v.
// MODE 1: v = x + p0 + p1 + p2 + p3 (p = [4][SEQ][DIM]); write xn = v.
// MODE 2: same sum; no xn write (final norm).
template <int MODE>
__global__ __launch_bounds__(256) void rmsnorm_fuse_k(
    const float* __restrict__ x, const float* __restrict__ p,
    const int* __restrict__ tokens, const float* __restrict__ emb,
    const float* __restrict__ gamma, float* __restrict__ xn,
    __bf16* __restrict__ h) {
  int n = blockIdx.x;
  float4 v;
  if (MODE == 0) {
    int tok = tokens[n];
    v = ((const float4*)(emb + (size_t)tok * DIM))[threadIdx.x];
    ((float4*)(xn + (size_t)n * DIM))[threadIdx.x] = v;
  } else {
    v = ((const float4*)(x + (size_t)n * DIM))[threadIdx.x];
#pragma unroll
    for (int z = 0; z < 4; z++) {
      float4 a = ((const float4*)(p + (size_t)(z * SEQ + n) * DIM))[threadIdx.x];
      v.x += a.x; v.y += a.y; v.z += a.z; v.w += a.w;
    }
    if (MODE == 1)
      ((float4*)(xn + (size_t)n * DIM))[threadIdx.x] = v;
  }
  float ssq = v.x * v.x + v.y * v.y + v.z * v.z + v.w * v.w;
  for (int m = 32; m >= 1; m >>= 1) ssq += __shfl_xor(ssq, m, 64);
  __shared__ float red[4];
  if ((threadIdx.x & 63) == 0) red[threadIdx.x >> 6] = ssq;
  __syncthreads();
  float tot = red[0] + red[1] + red[2] + red[3];
  float rs = rsqrtf(tot + 1e-5f) * 32.0f;
  float4 g = ((const float4*)gamma)[threadIdx.x];
  bf16x4 o;
  o[0] = (__bf16)(v.x * rs * g.x);
  o[1] = (__bf16)(v.y * rs * g.y);
  o[2] = (__bf16)(v.z * rs * g.z);
  o[3] = (__bf16)(v.w * rs * g.w);
  *(bf16x4*)(h + (size_t)n * DIM + threadIdx.x * 4) = o;
}

// ---------------- 2-phase GEMM (wi MODE 1, wo split-K MODE 0) --------------
// 128x128 tile, BK=64, 4 waves 2x2, XCD bn-stripe swizzle.
// MODE 0: LDS-repacked full-line fp32 stores to outf + z*SEQ*DIM (partial).
// MODE 1 (wi, B = permuted wiT): bn<8 or (bn==8,wc==0) -> q/k hi/lo split;
//   bn==8,wc==64 -> v scatter; bn>=9 -> ff*swish(gate) -> aof via LDS
//   repack (full-line bf16 stores).
template <int MODE>
__global__ __launch_bounds__(256) void gemm_bt_k(
    const __bf16* __restrict__ A, int lda,
    const __bf16* __restrict__ Bt, int ldb,
    float* __restrict__ outf, int ldc,
    __bf16* __restrict__ qh, __bf16* __restrict__ ql,
    __bf16* __restrict__ vT, __bf16* __restrict__ aof,
    int K) {
  __shared__ __bf16 lbuf[16384];   // lA | lB ; reused by epilogue repack
  __bf16* lA = lbuf;
  __bf16* lB = lbuf + 8192;
  const int t = threadIdx.x;
  const int lane = t & 63, wave = t >> 6;
  const int lo4 = lane & 15, hi2 = lane >> 4;
  const int nwg = gridDim.x * gridDim.y;
  const int orig = blockIdx.y * gridDim.x + blockIdx.x;   // hw dispatch id
  const int xcd = orig & 7, off = orig >> 3;
  const int qq = nwg >> 3, rr = nwg & 7;
  const int nid = (xcd < rr ? xcd * (qq + 1) : rr * (qq + 1) + (xcd - rr) * qq) + off;
  const int bm = nid % gridDim.y, bn = nid / gridDim.y;   // bm fastest
  const int k0 = blockIdx.z * K;
  const int wr = (wave >> 1) * 64, wc = (wave & 1) * 64;

  f32x4 acc[4][4];
#pragma unroll
  for (int m = 0; m < 4; m++)
#pragma unroll
    for (int n = 0; n < 4; n++) acc[m][n] = f32x4{0.f, 0.f, 0.f, 0.f};

  const int e0 = t * 8;
  const int e1 = 2048 + t * 8;
  const __bf16* gA0 = A + (size_t)(bm * 128 + (e0 >> 5)) * lda + (e0 & 31) + k0;
  const __bf16* gA1 = A + (size_t)(bm * 128 + (e1 >> 5)) * lda + (e1 & 31) + k0;
  const __bf16* gB0 = Bt + (size_t)(bn * 128 + (e0 >> 5)) * ldb + (e0 & 31) + k0;
  const __bf16* gB1 = Bt + (size_t)(bn * 128 + (e1 >> 5)) * ldb + (e1 & 31) + k0;
  __bf16* dA0 = &lA[wave * 512];
  __bf16* dA1 = &lA[2048 + wave * 512];
  __bf16* dB0 = &lB[wave * 512];
  __bf16* dB1 = &lB[2048 + wave * 512];

  for (int kt = 0; kt < K; kt += 64) {
    load_lds16(gA0 + kt, dA0);
    load_lds16(gA1 + kt, dA1);
    load_lds16(gB0 + kt, dB0);
    load_lds16(gB1 + kt, dB1);
    load_lds16(gA0 + kt + 32, dA0 + 4096);
    load_lds16(gA1 + kt + 32, dA1 + 4096);
    load_lds16(gB0 + kt + 32, dB0 + 4096);
    load_lds16(gB1 + kt + 32, dB1 + 4096);
    __syncthreads();
#pragma unroll
    for (int half = 0; half < 2; half++) {
      const __bf16* sA = &lA[half * 4096];
      const __bf16* sB = &lB[half * 4096];
      bf16x8 af[4], bf_[4];
#pragma unroll
      for (int m = 0; m < 4; m++)
        af[m] = *(const bf16x8*)&sA[(wr + m * 16 + lo4) * 32 + hi2 * 8];
#pragma unroll
      for (int n = 0; n < 4; n++)
        bf_[n] = *(const bf16x8*)&sB[(wc + n * 16 + lo4) * 32 + hi2 * 8];
#pragma unroll
      for (int m = 0; m < 4; m++)
#pragma unroll
        for (int n = 0; n < 4; n++)
          acc[m][n] = mfma16(af[m], bf_[n], acc[m][n]);
    }
    __syncthreads();
  }

  if (MODE == 0) {
    // repack each 64-row half into LDS fp32 [64][128]; stream 512B rows.
    float* lf = (float*)lbuf;
    float* op = outf + (size_t)blockIdx.z * SEQ * DIM;
#pragma unroll
    for (int half = 0; half < 2; half++) {
      if (half) __syncthreads();    // readers of half 0 done before overwrite
      if (wr == half * 64) {
#pragma unroll
        for (int m = 0; m < 4; m++)
#pragma unroll
          for (int n = 0; n < 4; n++)
#pragma unroll
            for (int j = 0; j < 4; j++)
              lf[(m * 16 + hi2 * 4 + j) * 128 + wc + n * 16 + lo4] = acc[m][n][j];
      }
      __syncthreads();              // drain ds_writes before cross-wave reads
#pragma unroll
      for (int i = 0; i < 8; i++) {   // 8 x 256 x 4 = 8192 floats = 64x128
        const int f = (i * 256 + t) * 4;
        const int r = f >> 7, cc = f & 127;
        f32x4 v4 = *(const f32x4*)&lf[f];
        __builtin_nontemporal_store(
            v4, (f32x4*)&op[(size_t)(bm * 128 + half * 64 + r) * ldc + bn * 128 + cc]);
      }
    }
  } else if (bn < 8 || (bn == 8 && wc == 0)) {
    // q (bn<8) and k (bn==8, cols 1024..1087): hi/lo split
#pragma unroll
    for (int m = 0; m < 4; m++) {
      const int rowb = bm * 128 + wr + m * 16 + hi2 * 4;
#pragma unroll
      for (int n = 0; n < 4; n++) {
        const int col = bn * 128 + wc + n * 16 + lo4;
#pragma unroll
        for (int j = 0; j < 4; j++) {
          float v = acc[m][n][j];
          __bf16 hi = (__bf16)v;
          qh[(size_t)(rowb + j) * QKW + col] = hi;
          ql[(size_t)(rowb + j) * QKW + col] = (__bf16)(v - (float)hi);
        }
      }
    }
  } else if (bn == 8) {
    // v (cols 1088..1151): direct transpose scatter to vT[64][SEQ]
#pragma unroll
    for (int m = 0; m < 4; m++) {
      const int rowb = bm * 128 + wr + m * 16 + hi2 * 4;
#pragma unroll
      for (int n = 0; n < 4; n++) {
        const int vcol = n * 16 + lo4;   // wc==64: col-1088 = n*16+lo4
#pragma unroll
        for (int j = 0; j < 4; j++)
          vT[(size_t)vcol * SEQ + rowb + j] = (__bf16)acc[m][n][j];
      }
    }
  } else {
    // interleaved ff/gate (bn>=9): fuse, repack into LDS bf16 [128][64],
    // stream 128B full-line rows (normal stores: aof is re-read by wo).
#pragma unroll
    for (int m = 0; m < 4; m++) {
      const int r0 = wr + m * 16 + hi2 * 4;
#pragma unroll
      for (int np = 0; np < 4; np += 2) {
        const int lc = ((wc >> 5) + (np >> 1)) * 16 + lo4;   // 0..63
#pragma unroll
        for (int j = 0; j < 4; j++) {
          float ff = acc[m][np][j];
          float gg = acc[m][np + 1][j];
          float s = gg / (1.f + expf(-gg));
          lbuf[(r0 + j) * 64 + lc] = (__bf16)(ff * s);
        }
      }
    }
    __syncthreads();                // drain ds_writes before cross-wave reads
    const int acol0 = 1024 + (bn - 9) * 64;
#pragma unroll
    for (int i = 0; i < 4; i++) {   // 4 x 256 x 8 = 8192 bf16 = 128x64
      const int e = (i * 256 + t) * 8;
      const int r = e >> 6, cc = e & 63;
      bf16x8 v8 = *(const bf16x8*)&lbuf[e];
      *(bf16x8*)&aof[(size_t)(bm * 128 + r) * AFW + acol0 + cc] = v8;
    }
  }
}

// ---------------- 256x256 8-phase GEMM (logits) ----------------------------
// LDS-repacked epilogue: full-cache-line float4 nontemporal stores.
__global__ __launch_bounds__(512, 1) void gemm256_k(
    const __bf16* __restrict__ A, const __bf16* __restrict__ Bt,
    float* __restrict__ C, int ldc, int K) {
  __shared__ __bf16 lds[65536];   // A: elems [0,32768), B: [32768,65536)
  const int t = threadIdx.x;
  const int lane = t & 63, w = t >> 6;
  const int lo4 = lane & 15, hi2 = lane >> 4;
  const int wr = w >> 2, wc = w & 3;       // 2 x 4 wave grid
  const int nwg = gridDim.x * gridDim.y;
  const int orig = blockIdx.y * gridDim.x + blockIdx.x;
  const int xcd = orig & 7, off = orig >> 3;
  const int qq = nwg >> 3, rr = nwg & 7;
  const int nid = (xcd < rr ? xcd * (qq + 1) : rr * (qq + 1) + (xcd - rr) * qq) + off;
  const int bm = nid % gridDim.y, bn = nid / gridDim.y;

  const int srow = lane >> 2;
  const int scol = ((lane & 3) * 8) ^ ((lane >> 5) << 4);   // pre-swizzled src
  const __bf16* gA = A + (size_t)(bm * 256 + srow) * K + scol;
  const __bf16* gB = Bt + (size_t)(bn * 256 + srow) * K + scol;
  const int cpr = (hi2 * 8) ^ ((lo4 >= 8) ? 16 : 0);        // read-side XOR

  auto STAGE = [&](int kt, int ks, int isB) {
    const __bf16* g = (isB ? gB : gA) + kt * 64 + ks * 32;
    __bf16* l = &lds[isB * 32768 + (kt & 1) * 16384 + ks * 8192 + (2 * w) * 512];
    load_lds16(g + (size_t)(2 * w) * 16 * K, l);
    load_lds16(g + (size_t)(2 * w + 1) * 16 * K, l + 512);
  };

  f32x4 acc[8][4];
#pragma unroll
  for (int m = 0; m < 8; m++)
#pragma unroll
    for (int n = 0; n < 4; n++) acc[m][n] = f32x4{0.f, 0.f, 0.f, 0.f};

  STAGE(0, 0, 0); STAGE(0, 0, 1); STAGE(0, 1, 0); STAGE(0, 1, 1);

  const int NIT = K >> 7;
  bf16x8 bfr[4];
  for (int it = 0; it < NIT; ++it) {
#pragma unroll
    for (int p = 0; p < 8; ++p) {
      const int g = p >> 2;
      const int u = p & 3;
      const int ks = u >> 1, mh = u & 1;
      const int kt = 2 * it + g;
      const bool dostage = (it < NIT - 1) || (g == 0);
      if ((u & 1) == 0) {
        if (it == NIT - 1 && g == 1 && u == 2)
          asm volatile("s_waitcnt vmcnt(0)" ::: "memory");
        else
          asm volatile("s_waitcnt vmcnt(4)" ::: "memory");
        __builtin_amdgcn_s_barrier();
      }
      const int abase = g * 16384 + ks * 8192 + lo4 * 32 + cpr;
      if ((u & 1) == 0) {
#pragma unroll
        for (int n = 0; n < 4; n++)
          bfr[n] = *(const bf16x8*)&lds[32768 + abase + (wc * 4 + n) * 512];
      }
      bf16x8 af[4];
#pragma unroll
      for (int mm = 0; mm < 4; mm++)
        af[mm] = *(const bf16x8*)&lds[abase + (wr * 8 + mh * 4 + mm) * 512];
      if (dostage) STAGE(kt + 1, ks, u & 1);
      __builtin_amdgcn_s_setprio(1);
#pragma unroll
      for (int mm = 0; mm < 4; mm++)
#pragma unroll
        for (int n = 0; n < 4; n++)
          acc[mh * 4 + mm][n] = mfma16(af[mm], bfr[n], acc[mh * 4 + mm][n]);
      __builtin_amdgcn_s_setprio(0);
    }
  }

  // ---- epilogue: repack -> LDS fp32 [128][256] per half, wide stores ----
  float* lf = (float*)lds;
#pragma unroll
  for (int half = 0; half < 2; half++) {
    __syncthreads();                // readers done (main loop / prev half)
    if (wr == half) {
#pragma unroll
      for (int m = 0; m < 8; m++) {
        const int r = m * 16 + hi2 * 4;
#pragma unroll
        for (int n = 0; n < 4; n++) {
          const int cc = wc * 64 + n * 16 + lo4;
#pragma unroll
          for (int j = 0; j < 4; j++)
            lf[(r + j) * 256 + cc] = acc[m][n][j];
        }
      }
    }
    __syncthreads();                // drain ds_writes before cross-wave reads
    const int rowbase = bm * 256 + half * 128;
    const int colbase = bn * 256;
#pragma unroll
    for (int itq = 0; itq < 16; itq++) {
      const int f = (itq * 512 + t) * 4;   // flat float index in [128][256]
      const int r = f >> 8;
      const int cc = f & 255;
      f32x4 v4 = *(const f32x4*)&lf[f];
      __builtin_nontemporal_store(
          v4, (f32x4*)&C[(size_t)(rowbase + r) * ldc + colbase + cc]);
    }
  }
}

// ---------------- flash attention (MQA, causal + ALiBi-on-j) ---------------
// 1024 blocks x 4 waves.  Each block: head h = b&15, chunk pair (s, 127-s).
// Wave pair (pr) splits the KV range of chunk c; LDS LSE merge at end.
__global__ __launch_bounds__(256, 4) void flash_k(
    const __bf16* __restrict__ qh, const __bf16* __restrict__ ql,
    const __bf16* __restrict__ vT, __bf16* __restrict__ aof) {
  const int t = threadIdx.x;
  const int lane = t & 63, wave = t >> 6;
  const int lo4 = lane & 15, hi2 = lane >> 4;
  const int b = blockIdx.x;
  const int h = b & 15;
  const int s = b >> 4;                     // 0..63
  const int pr = wave >> 1, half = wave & 1;
  const int c = pr ? (127 - s) : s;         // q-chunk 0..127
  const int qrow0 = c * 16;
  const int nt = (c >> 2) + 1;
  const int ntA = (nt + 1) >> 1;
  const int jt0 = half ? ntA : 0;
  const int jtE = half ? nt : ntA;
  const float slope2 = exp2f(-0.5f * (float)(h + 1)) * LOG2E;
  const float scale2 = 0.125f * LOG2E;

  __shared__ __bf16 lP[4][16][72];          // per-wave P tile
  __shared__ float smO[2][2][16][65];       // [pair][half][row][col] O halves
  __shared__ float sml[2][2][16][2];        // [pair][half][row][{m,l}]
  __bf16 (*lPw)[72] = lP[wave];

  bf16x8 qhf[2], qlf[2];
#pragma unroll
  for (int kk = 0; kk < 2; kk++) {
    size_t qoff = (size_t)(qrow0 + lo4) * QKW + h * 64 + kk * 32 + hi2 * 8;
    qhf[kk] = *(const bf16x8*)(qh + qoff);
    qlf[kk] = *(const bf16x8*)(ql + qoff);
  }

  float jb[4][4];
#pragma unroll
  for (int f = 0; f < 4; f++)
#pragma unroll
    for (int r = 0; r < 4; r++)
      jb[f][r] = slope2 * (float)(jt0 * 64 + f * 16 + hi2 * 4 + r);
  const float dj = slope2 * 64.0f;
  const int iq = qrow0 + lo4;

  f32x4 O[4];
#pragma unroll
  for (int f = 0; f < 4; f++) O[f] = f32x4{0.f, 0.f, 0.f, 0.f};
  float mr = -1e30f, lr = 0.f;

  for (int jt = jt0; jt < jtE; ++jt) {
    f32x4 sc[4];
#pragma unroll
    for (int f = 0; f < 4; f++) sc[f] = f32x4{0.f, 0.f, 0.f, 0.f};
    __builtin_amdgcn_s_setprio(1);
#pragma unroll
    for (int kk = 0; kk < 2; kk++) {
#pragma unroll
      for (int f = 0; f < 4; f++) {
        size_t koff = (size_t)(jt * 64 + f * 16 + lo4) * QKW + 1024 + kk * 32 + hi2 * 8;
        bf16x8 khf = *(const bf16x8*)(qh + koff);
        bf16x8 klf = *(const bf16x8*)(ql + koff);
        sc[f] = mfma16(khf, qlf[kk], sc[f]);
        sc[f] = mfma16(klf, qhf[kk], sc[f]);
        sc[f] = mfma16(khf, qhf[kk], sc[f]);
      }
    }
    __builtin_amdgcn_s_setprio(0);

    float pv[4][4];
    float tmax = -1e30f;
#pragma unroll
    for (int f = 0; f < 4; f++)
#pragma unroll
      for (int r = 0; r < 4; r++) {
        const int j = jt * 64 + f * 16 + hi2 * 4 + r;
        float v = fmaf(sc[f][r], scale2, jb[f][r]);
        if (j > iq) v = -1e30f;
        pv[f][r] = v;
        tmax = fmaxf(tmax, v);
      }
    tmax = fmaxf(tmax, __shfl_xor(tmax, 16, 64));
    tmax = fmaxf(tmax, __shfl_xor(tmax, 32, 64));
    float mn = fmaxf(mr, tmax);
    float corr = exp2f(mr - mn);
    mr = mn;
    float rs = 0.f;
#pragma unroll
    for (int f = 0; f < 4; f++)
#pragma unroll
      for (int r = 0; r < 4; r++) {
        float pe = exp2f(pv[f][r] - mn);
        __bf16 pb = (__bf16)pe;
        lPw[lo4][f * 16 + hi2 * 4 + r] = pb;
        rs += (float)pb;
      }
    rs += __shfl_xor(rs, 16, 64);
    rs += __shfl_xor(rs, 32, 64);
    lr = lr * corr + rs;
    float co[4];
#pragma unroll
    for (int r = 0; r < 4; r++)
      co[r] = __shfl(corr, (lane & 48) + hi2 * 4 + r, 64);
#pragma unroll
    for (int f = 0; f < 4; f++)
#pragma unroll
      for (int r = 0; r < 4; r++) O[f][r] *= co[r];

    __builtin_amdgcn_s_setprio(1);
#pragma unroll
    for (int kk = 0; kk < 2; kk++) {
      bf16x8 pa = *(const bf16x8*)&lPw[lo4][kk * 32 + hi2 * 8];
#pragma unroll
      for (int f = 0; f < 4; f++) {
        bf16x8 vb = *(const bf16x8*)(vT + (size_t)(f * 16 + lo4) * SEQ + jt * 64 + kk * 32 + hi2 * 8);
        O[f] = mfma16(pa, vb, O[f]);
      }
    }
    __builtin_amdgcn_s_setprio(0);

#pragma unroll
    for (int f = 0; f < 4; f++)
#pragma unroll
      for (int r = 0; r < 4; r++) jb[f][r] += dj;
  }

  // ---- merge the two KV-halves via LDS ----
#pragma unroll
  for (int f = 0; f < 4; f++)
#pragma unroll
    for (int r = 0; r < 4; r++)
      smO[pr][half][hi2 * 4 + r][f * 16 + lo4] = O[f][r];
  if (hi2 == 0) {
    sml[pr][half][lo4][0] = mr;
    sml[pr][half][lo4][1] = lr;
  }
  __syncthreads();
  if (half == 0) {
#pragma unroll
    for (int r = 0; r < 4; r++) {
      const int row = hi2 * 4 + r;
      float mA = sml[pr][0][row][0], lA = sml[pr][0][row][1];
      float mB = sml[pr][1][row][0], lB = sml[pr][1][row][1];
      float mS = fmaxf(mA, mB);
      float cA = exp2f(mA - mS), cB = exp2f(mB - mS);
      float li = lA * cA + lB * cB;
#pragma unroll
      for (int f = 0; f < 4; f++) {
        float v = (smO[pr][0][row][f * 16 + lo4] * cA +
                   smO[pr][1][row][f * 16 + lo4] * cB) / li;
        aof[(size_t)(qrow0 + row) * AFW + h * 64 + f * 16 + lo4] = (__bf16)v;
      }
    }
  }
}

// ---------------------------------------------------------------------------

extern "C" void kernel_launch(void* const* d_in, const int* in_sizes, int n_in,
                              void* d_out, int out_size, void* d_ws, size_t ws_size,
                              hipStream_t stream) {
  const int* tokens  = (const int*)d_in[0];
  const float* emb   = (const float*)d_in[1];
  const float* wi    = (const float*)d_in[2];
  const float* awo   = (const float*)d_in[3];
  const float* fwo   = (const float*)d_in[4];
  const float* gam   = (const float*)d_in[5];
  const float* fgam  = (const float*)d_in[6];
  float* out = (float*)d_out;

  char* wsp = (char*)d_ws;
  size_t woff = 0;
  auto walloc = [&](size_t b) { void* p = wsp + woff; woff += (b + 255) & ~(size_t)255; return p; };
  __bf16* embb = (__bf16*)walloc((size_t)VOCAB * DIM * 2);
  __bf16* h    = (__bf16*)walloc((size_t)SEQ * DIM * 2);

  char* op = (char*)d_out;
  size_t ooff = 0;
  auto oalloc = [&](size_t b) { void* p = op + ooff; ooff += (b + 255) & ~(size_t)255; return p; };
  float*  xA    = (float*)oalloc((size_t)SEQ * DIM * 4);
  float*  xB    = (float*)oalloc((size_t)SEQ * DIM * 4);
  float*  pp    = (float*)oalloc((size_t)4 * SEQ * DIM * 4);  // split-K partials
  __bf16* qhb   = (__bf16*)oalloc((size_t)SEQ * QKW * 2);
  __bf16* qlb   = (__bf16*)oalloc((size_t)SEQ * QKW * 2);
  __bf16* vT    = (__bf16*)oalloc((size_t)DHEAD * SEQ * 2);
  __bf16* aof   = (__bf16*)oalloc((size_t)SEQ * AFW * 2);
  __bf16* wiT4  = (__bf16*)oalloc((size_t)4 * FUSEN * DIM * 2);  // 76.6 MB
  __bf16* BT24  = (__bf16*)oalloc((size_t)4 * DIM * AFW * 2);    // 41.9 MB
  (void)ws_size; (void)in_sizes; (void)n_in; (void)out_size;

  cast_k<<<(VOCAB * DIM / 8 + 255) / 256, 256, 0, stream>>>(emb, embb, VOCAB * DIM / 8);
  // batched weight prep (all layers, hoisted)
  transpose_wi_k<<<dim3(FUSEN / 64, DIM / 64, 4), 256, 0, stream>>>(wi, wiT4);
  transpose_b_k<<<dim3(DIM / 64, DIM / 64, 4), 256, 0, stream>>>(
      awo, BT24, DIM, DIM, AFW, 0, (size_t)DIM * AFW);
  transpose_b_k<<<dim3(DIM / 64, FFIN / 64, 4), 256, 0, stream>>>(
      fwo, BT24, FFIN, DIM, AFW, 1024, (size_t)DIM * AFW);

  float* x = xA;
  float* xn = xB;
  for (int l = 0; l < 4; l++) {
    if (l == 0) {
      // gather + rmsnorm fused: writes x (=xA) and h
      rmsnorm_fuse_k<0><<<SEQ, 256, 0, stream>>>(
          nullptr, nullptr, tokens, emb, gam, x, h);
    } else {
      rmsnorm_fuse_k<1><<<SEQ, 256, 0, stream>>>(
          x, pp, nullptr, nullptr, gam + l * DIM, xn, h);
      float* tmp = x; x = xn; xn = tmp;
    }
    gemm_bt_k<1><<<dim3(FUSEN / 128, SEQ / 128), 256, 0, stream>>>(
        h, DIM, wiT4 + (size_t)l * FUSEN * DIM, DIM, nullptr, 0,
        qhb, qlb, vT, aof, DIM);
    flash_k<<<dim3(1024), 256, 0, stream>>>(qhb, qlb, vT, aof);
    gemm_bt_k<0><<<dim3(DIM / 128, SEQ / 128, 4), 256, 0, stream>>>(
        aof, AFW, BT24 + (size_t)l * DIM * AFW, AFW, pp, DIM,
        nullptr, nullptr, nullptr, nullptr, AFW / 4);
  }

  rmsnorm_fuse_k<2><<<SEQ, 256, 0, stream>>>(
      x, pp, nullptr, nullptr, fgam, nullptr, h);
  gemm256_k<<<dim3(VOCAB / 256, SEQ / 256), 512, 0, stream>>>(
      h, embb, out, VOCAB, DIM);
}